// Round 1
// baseline (1948.156 us; speedup 1.0000x reference)
//
#include <hip/hip_runtime.h>
#include <cstdint>
#include <cstddef>

#define NQT   150
#define WAYT  5
#define CCH   640
#define NPIX  100
#define PADB  101

// const-pack offsets (floats)
#define CP_W2L   0      // 2304: [cin][tap(9)][co(16)]
#define CP_WEFF  2304   // 144:  [ci][tap]
#define CP_A     2448   // 16
#define CP_B     2464   // 16
#define CP_G2    2480   // 16
#define CP_B2    2496   // 16
#define CP_W20   2512   // 9
#define CP_W10   2521   // 9
#define CP_SC    2530   // g2_0, b2_0, g1_0, b1_0, K
#define CP_SIZE  2560

// ---------------- prep: reorder / fold weights into const pack ----------------
__global__ __launch_bounds__(256) void k_prep(
    const float* __restrict__ s0_w2, const float* __restrict__ s0_g2, const float* __restrict__ s0_b2,
    const float* __restrict__ s0_w1, const float* __restrict__ s0_g1, const float* __restrict__ s0_b1,
    const float* __restrict__ s0_wp, const float* __restrict__ s0_gp, const float* __restrict__ s0_bp,
    const float* __restrict__ s1_w2, const float* __restrict__ s1_g2, const float* __restrict__ s1_b2,
    const float* __restrict__ s1_w1, const float* __restrict__ s1_g1, const float* __restrict__ s1_b1,
    const float* __restrict__ s1_wp, const float* __restrict__ s1_gp, const float* __restrict__ s1_bp,
    float* __restrict__ cp)
{
  const int t = threadIdx.x;
  // s1_w2 flat [co][cin][ku][kv] -> [cin][n][co]
  for (int e = t; e < 2304; e += 256){
    int co = e / 144, r = e % 144, cin = r / 9, n = r % 9;
    cp[CP_W2L + (cin*9 + n)*16 + co] = s1_w2[e];
  }
  const float gp1 = s1_gp[0];
  for (int e = t; e < 144; e += 256){
    int ci = e / 9, n = e % 9;
    float s = 0.f;
    for (int co = 0; co < 16; co++)
      s += gp1 * s1_wp[co] * s1_g1[co] * s1_w1[(co*16 + ci)*9 + n];
    cp[CP_WEFF + e] = s;
  }
  if (t < 16){
    cp[CP_A + t]  = s0_gp[t] * s0_wp[t];
    cp[CP_B + t]  = s0_bp[t];
    cp[CP_G2 + t] = s1_g2[t];
    cp[CP_B2 + t] = s1_b2[t];
  }
  if (t < 9){ cp[CP_W20 + t] = s0_w2[t]; cp[CP_W10 + t] = s0_w1[t]; }
  if (t == 0){
    cp[CP_SC + 0] = s0_g2[0]; cp[CP_SC + 1] = s0_b2[0];
    cp[CP_SC + 2] = s0_g1[0]; cp[CP_SC + 3] = s0_b1[0];
    float kk = 0.f;
    for (int co = 0; co < 16; co++) kk += s1_wp[co] * s1_b1[co];
    cp[CP_SC + 4] = gp1 * kk + s1_bp[0];
  }
}

// ---------------- per-(image,pixel) channel means ----------------
__global__ __launch_bounds__(256) void k_means(
    const float* __restrict__ spt, const float* __restrict__ qry,
    float* __restrict__ sptm, float* __restrict__ qrym)
{
  const int idx = blockIdx.x * 256 + threadIdx.x;
  if (idx >= 500 + NQT * NPIX) return;
  const float* src; float* dst;
  if (idx < 500){
    int n = idx / NPIX, ij = idx % NPIX;
    src = spt + (size_t)n * CCH * NPIX + ij; dst = sptm + idx;
  } else {
    int k = idx - 500; int n = k / NPIX, ij = k % NPIX;
    src = qry + (size_t)n * CCH * NPIX + ij; dst = qrym + k;
  }
  float s = 0.f;
  for (int c = 0; c < CCH; c++) s += src[(size_t)c * NPIX];
  *dst = s * (1.f / CCH);
}

// ---------------- feat: 1x1 conv 640->64 + affine + relu + L2-normalize ----------------
__global__ __launch_bounds__(256) void k_feat(
    const float* __restrict__ spt, const float* __restrict__ qry,
    const float* __restrict__ sptm, const float* __restrict__ qrym,
    const float* __restrict__ W, const float* __restrict__ gg, const float* __restrict__ bb,
    float* __restrict__ s_feat, float* __restrict__ q_feat)
{
  __shared__ float y[6400];
  __shared__ float invn[100];
  const int n = blockIdx.x;
  const float* x; const float* m; float* out;
  if (n < 5){ x = spt + (size_t)n * 64000; m = sptm + n * 100; out = s_feat + (size_t)n * 6400; }
  else { x = qry + (size_t)(n-5) * 64000; m = qrym + (size_t)(n-5) * 100; out = q_feat + (size_t)(n-5) * 6400; }
  const int t = threadIdx.x;
  const int o = t >> 2, gq = t & 3;
  float acc[25];
  #pragma unroll
  for (int k = 0; k < 25; k++) acc[k] = 0.f;
  float wsum = 0.f;
  const float* wr = W + (size_t)o * 640;
  for (int c = 0; c < 640; c++){
    const float wv = wr[c];
    wsum += wv;
    const float* xr = x + (size_t)c * 100 + gq;
    #pragma unroll
    for (int k = 0; k < 25; k++) acc[k] += wv * xr[4*k];
  }
  const float go = gg[o], bo = bb[o];
  #pragma unroll
  for (int k = 0; k < 25; k++){
    const int ij = gq + 4*k;
    float v = go * (acc[k] - wsum * m[ij]) + bo;
    y[o*100 + ij] = fmaxf(v, 0.f);
  }
  __syncthreads();
  if (t < 100){
    float s = 0.f;
    #pragma unroll
    for (int o2 = 0; o2 < 64; o2++){ float v = y[o2*100 + t]; s += v*v; }
    invn[t] = 1.f / fmaxf(sqrtf(s), 1e-8f);
  }
  __syncthreads();
  for (int e = t; e < 6400; e += 256) out[e] = y[e] * invn[e % 100];
}

// ---------------- fused corr + SepConv4d layer0 + relu + layer1 -> F ----------------
__global__ __launch_bounds__(128) void k_main(
    const float* __restrict__ s_feat, const float* __restrict__ q_feat,
    const float* __restrict__ cp, float* __restrict__ F)
{
  __shared__ float buf[NPIX * PADB];            // corr plane / z, [uv][hw] padded
  __shared__ __align__(16) float t1s[3200];     // corr tiles / t1[2][16][100]
  const int pair = blockIdx.x;
  const int q = pair / WAYT, w = pair % WAYT;
  const int t = threadIdx.x;

  // ---- corr: col[uv] = sum_c s[w,c,uv]*q[q,c,hw=t], accumulated over 4 c-tiles ----
  float col[100];
  #pragma unroll
  for (int i = 0; i < 100; i++) col[i] = 0.f;

  for (int ct = 0; ct < 4; ct++){
    __syncthreads();
    for (int e = t; e < 1600; e += 128){
      t1s[e]        = s_feat[w*6400 + ct*1600 + e];
      t1s[1600 + e] = q_feat[(size_t)q*6400 + ct*1600 + e];
    }
    __syncthreads();
    if (t < 100){
      float qr[16];
      #pragma unroll
      for (int cc = 0; cc < 16; cc++) qr[cc] = t1s[1600 + cc*100 + t];
      #pragma unroll
      for (int u4 = 0; u4 < 25; u4++){
        float a0=0.f, a1=0.f, a2=0.f, a3=0.f;
        #pragma unroll
        for (int cc = 0; cc < 16; cc++){
          const float4 sv = *(const float4*)&t1s[cc*100 + u4*4];
          a0 += sv.x*qr[cc]; a1 += sv.y*qr[cc];
          a2 += sv.z*qr[cc]; a3 += sv.w*qr[cc];
        }
        col[u4*4+0]+=a0; col[u4*4+1]+=a1; col[u4*4+2]+=a2; col[u4*4+3]+=a3;
      }
    }
  }

  // ---- layer0 conv over (u,v) + affine + relu -> buf ----
  if (t < 100){
    float w20r[9];
    #pragma unroll
    for (int i = 0; i < 9; i++) w20r[i] = cp[CP_W20 + i];
    const float g20 = cp[CP_SC+0], b20 = cp[CP_SC+1];
    #pragma unroll
    for (int u = 0; u < 10; u++){
      #pragma unroll
      for (int v = 0; v < 10; v++){
        float o = 0.f;
        #pragma unroll
        for (int du = 0; du < 3; du++){
          const int uu = u + du - 1;
          if (uu < 0 || uu > 9) continue;
          #pragma unroll
          for (int dv = 0; dv < 3; dv++){
            const int vv = v + dv - 1;
            if (vv < 0 || vv > 9) continue;
            o += w20r[du*3+dv] * col[uu*10+vv];
          }
        }
        o = g20*o + b20;
        buf[(u*10+v)*PADB + t] = fmaxf(o, 0.f);
      }
    }
  }
  __syncthreads();

  // ---- layer0 conv over (h,w) + affine -> buf = z ----
  if (t < 100){
    float row[100];
    #pragma unroll
    for (int k = 0; k < 100; k++) row[k] = buf[t*PADB + k];
    float w10r[9];
    #pragma unroll
    for (int i = 0; i < 9; i++) w10r[i] = cp[CP_W10 + i];
    const float g10 = cp[CP_SC+2], b10 = cp[CP_SC+3];
    #pragma unroll
    for (int h = 0; h < 10; h++){
      #pragma unroll
      for (int ww = 0; ww < 10; ww++){
        float o = 0.f;
        #pragma unroll
        for (int dh = 0; dh < 3; dh++){
          const int hh2 = h + dh - 1;
          if (hh2 < 0 || hh2 > 9) continue;
          #pragma unroll
          for (int dw = 0; dw < 3; dw++){
            const int ww2 = ww + dw - 1;
            if (ww2 < 0 || ww2 > 9) continue;
            o += w10r[dh*3+dw] * row[hh2*10+ww2];
          }
        }
        buf[t*PADB + h*10+ww] = g10*o + b10;
      }
    }
  }
  __syncthreads();

  // ---- layer1: per (u,v)-pair chunk, t = hw ----
  const float Kc = cp[CP_SC+4];
  const int hT = t / 10, wT = t % 10;
  #pragma unroll 1
  for (int chunk = 0; chunk < 50; chunk++){
    const int u = chunk / 5, v0 = (chunk % 5) * 2;
    if (t < 100){
      float acc0[16], acc1[16];
      #pragma unroll
      for (int co = 0; co < 16; co++){ acc0[co]=0.f; acc1[co]=0.f; }
      #pragma unroll
      for (int du = 0; du < 3; du++){
        const int ur = u + du - 1;
        if (ur >= 0 && ur < 10){
          float z4[4]; bool zok[4];
          #pragma unroll
          for (int k = 0; k < 4; k++){
            const int vc = v0 - 1 + k;
            zok[k] = (vc >= 0 && vc < 10);
            z4[k] = zok[k] ? buf[(ur*10+vc)*PADB + t] : 0.f;
          }
          #pragma unroll
          for (int cin = 0; cin < 16; cin++){
            const float A = cp[CP_A + cin], B = cp[CP_B + cin];
            float r4[4];
            #pragma unroll
            for (int k = 0; k < 4; k++)
              r4[k] = zok[k] ? fmaxf(A*z4[k] + B, 0.f) : 0.f;  // padded input -> 0, NOT relu(B)
            #pragma unroll
            for (int dv = 0; dv < 3; dv++){
              const float4* wp4 = (const float4*)&cp[CP_W2L + (cin*9 + du*3 + dv)*16];
              const float ra = r4[dv], rb = r4[dv+1];
              #pragma unroll
              for (int c4 = 0; c4 < 4; c4++){
                const float4 wq = wp4[c4];
                acc0[c4*4+0] += wq.x*ra; acc1[c4*4+0] += wq.x*rb;
                acc0[c4*4+1] += wq.y*ra; acc1[c4*4+1] += wq.y*rb;
                acc0[c4*4+2] += wq.z*ra; acc1[c4*4+2] += wq.z*rb;
                acc0[c4*4+3] += wq.w*ra; acc1[c4*4+3] += wq.w*rb;
              }
            }
          }
        }
      }
      #pragma unroll
      for (int co = 0; co < 16; co++){
        const float g2 = cp[CP_G2 + co], b2 = cp[CP_B2 + co];
        t1s[co*100 + t]        = fmaxf(g2*acc0[co] + b2, 0.f);
        t1s[1600 + co*100 + t] = fmaxf(g2*acc1[co] + b2, 0.f);
      }
    }
    __syncthreads();
    if (t < 100){
      float o0 = Kc, o1 = Kc;
      #pragma unroll
      for (int ci = 0; ci < 16; ci++){
        #pragma unroll
        for (int dh = 0; dh < 3; dh++){
          const int hh2 = hT + dh - 1;
          if (hh2 < 0 || hh2 > 9) continue;
          #pragma unroll
          for (int dw = 0; dw < 3; dw++){
            const int ww2 = wT + dw - 1;
            if (ww2 < 0 || ww2 > 9) continue;
            const float we = cp[CP_WEFF + ci*9 + dh*3 + dw];
            const int idx = hh2*10 + ww2;
            o0 += we * t1s[ci*100 + idx];
            o1 += we * t1s[1600 + ci*100 + idx];
          }
        }
      }
      F[(size_t)pair*10000 + (u*10 + v0    )*100 + t] = o0;
      F[(size_t)pair*10000 + (u*10 + v0 + 1)*100 + t] = o1;
    }
    __syncthreads();
  }
}

// ---------------- gnorm + softmax attention + pooled cosine ----------------
__global__ __launch_bounds__(128) void k_attn(
    const float* __restrict__ F, const float* __restrict__ spt,
    const float* __restrict__ qry, const float* __restrict__ sptm,
    const float* __restrict__ qrym, float* __restrict__ out)
{
  __shared__ float buf[NPIX * PADB];
  __shared__ float st[800];    // col: m,is,M,Sinv | row: m,is,M,Sinv
  __shared__ float av[200];    // a_s[uv], a_q[hw]
  __shared__ float red[384];
  const int pair = blockIdx.x;
  const int q = pair / WAYT, w = pair % WAYT;
  const int t = threadIdx.x;

  for (int e = t; e < 10000; e += 128)
    buf[(e/100)*PADB + (e%100)] = F[(size_t)pair*10000 + e];
  __syncthreads();

  if (t < 100){
    // cs stats: over uv, for column hw = t
    float s = 0.f;
    for (int uv = 0; uv < 100; uv++) s += buf[uv*PADB + t];
    const float m = s * 0.01f;
    float ss = 0.f;
    for (int uv = 0; uv < 100; uv++){ const float d = buf[uv*PADB + t] - m; ss += d*d; }
    const float is_ = rsqrtf(ss * (1.f/99.f) + 1e-5f) * 0.2f;   // fold 1/TEMP_ATTN
    float M = -3.4e38f;
    for (int uv = 0; uv < 100; uv++) M = fmaxf(M, (buf[uv*PADB + t] - m) * is_);
    float S = 0.f;
    for (int uv = 0; uv < 100; uv++) S += __expf((buf[uv*PADB + t] - m) * is_ - M);
    st[t] = m; st[100+t] = is_; st[200+t] = M; st[300+t] = 1.f / S;
  }
  __syncthreads();
  if (t < 100){
    // a_s[uv = t]
    float a = 0.f;
    for (int hw = 0; hw < 100; hw++){
      const float c = (buf[t*PADB + hw] - st[hw]) * st[100+hw] - st[200+hw];
      a += __expf(c) * st[300+hw];
    }
    av[t] = a;
    // cq stats: over hw, for row uv = t
    float s = 0.f;
    for (int k = 0; k < 100; k++) s += buf[t*PADB + k];
    const float m = s * 0.01f;
    float ss = 0.f;
    for (int k = 0; k < 100; k++){ const float d = buf[t*PADB + k] - m; ss += d*d; }
    const float is_ = rsqrtf(ss * (1.f/99.f) + 1e-5f) * 0.2f;
    float M = -3.4e38f;
    for (int k = 0; k < 100; k++) M = fmaxf(M, (buf[t*PADB + k] - m) * is_);
    float S = 0.f;
    for (int k = 0; k < 100; k++) S += __expf((buf[t*PADB + k] - m) * is_ - M);
    st[400+t] = m; st[500+t] = is_; st[600+t] = M; st[700+t] = 1.f / S;
  }
  __syncthreads();
  if (t < 100){
    // a_q[hw = t]
    float a = 0.f;
    for (int uv = 0; uv < 100; uv++){
      const float c = (buf[uv*PADB + t] - st[400+uv]) * st[500+uv] - st[600+uv];
      a += __expf(c) * st[700+uv];
    }
    av[100+t] = a;
  }
  __syncthreads();

  // pooled prototypes + cosine: threads over channels
  float d0 = 0.f, d1 = 0.f, d2 = 0.f;
  for (int c = t; c < CCH; c += 128){
    const float* srow  = spt + (size_t)w*CCH*NPIX + (size_t)c*NPIX;
    const float* qrow  = qry + (size_t)q*CCH*NPIX + (size_t)c*NPIX;
    const float* smrow = sptm + w*NPIX;
    const float* qmrow = qrym + q*NPIX;
    float sp = 0.f, qp = 0.f;
    for (int ij = 0; ij < 100; ij++){
      sp += av[ij]      * (srow[ij] - smrow[ij]);
      qp += av[100+ij]  * (qrow[ij] - qmrow[ij]);
    }
    sp *= 0.01f; qp *= 0.01f;
    d0 += sp*qp; d1 += sp*sp; d2 += qp*qp;
  }
  red[t] = d0; red[128+t] = d1; red[256+t] = d2;
  __syncthreads();
  if (t == 0){
    float e0 = 0.f, e1 = 0.f, e2 = 0.f;
    for (int i = 0; i < 128; i++){ e0 += red[i]; e1 += red[128+i]; e2 += red[256+i]; }
    const float den = fmaxf(sqrtf(e1), 1e-8f) * fmaxf(sqrtf(e2), 1e-8f);
    out[pair] = (e0 / den) * 5.0f;   // / TEMP(0.2)
  }
}

extern "C" void kernel_launch(void* const* d_in, const int* in_sizes, int n_in,
                              void* d_out, int out_size, void* d_ws, size_t ws_size,
                              hipStream_t stream)
{
  (void)in_sizes; (void)n_in; (void)out_size; (void)ws_size;
  const float* spt = (const float*)d_in[0];
  const float* qry = (const float*)d_in[1];
  const float* Wc  = (const float*)d_in[2];
  const float* gc  = (const float*)d_in[3];
  const float* bc  = (const float*)d_in[4];

  float* ws    = (float*)d_ws;
  float* cp    = ws;                 // 2560
  float* sptm  = ws + 2560;          // 512
  float* qrym  = ws + 3072;          // 15104
  float* sfeat = ws + 18176;         // 32000
  float* qfeat = ws + 50176;         // 960000
  float* F     = ws + 1010176;       // 7,500,000  (end ~34 MB)

  k_prep<<<1, 256, 0, stream>>>(
      (const float*)d_in[5],  (const float*)d_in[6],  (const float*)d_in[7],
      (const float*)d_in[8],  (const float*)d_in[9],  (const float*)d_in[10],
      (const float*)d_in[11], (const float*)d_in[12], (const float*)d_in[13],
      (const float*)d_in[14], (const float*)d_in[15], (const float*)d_in[16],
      (const float*)d_in[17], (const float*)d_in[18], (const float*)d_in[19],
      (const float*)d_in[20], (const float*)d_in[21], (const float*)d_in[22],
      cp);
  k_means<<<(500 + NQT*NPIX + 255)/256, 256, 0, stream>>>(spt, qry, sptm, qrym);
  k_feat<<<155, 256, 0, stream>>>(spt, qry, sptm, qrym, Wc, gc, bc, sfeat, qfeat);
  k_main<<<NQT*WAYT, 128, 0, stream>>>(sfeat, qfeat, cp, F);
  k_attn<<<NQT*WAYT, 128, 0, stream>>>(F, spt, qry, sptm, qrym, (float*)d_out);
}

// Round 2
// 1137.483 us; speedup vs baseline: 1.7127x; 1.7127x over previous
//
#include <hip/hip_runtime.h>
#include <hip/hip_fp16.h>
#include <cstdint>
#include <cstddef>

#define NQT   150
#define WAYT  5
#define CCH   640
#define NPIX  100
#define PADB  101

// const-pack offsets (floats)
#define CP_W2L   0      // 2304: [cin][tap(9)][co(16)]
#define CP_WEFF  2304   // 144:  [ci][tap]
#define CP_A     2448   // 16
#define CP_B     2464   // 16
#define CP_G2    2480   // 16
#define CP_B2    2496   // 16
#define CP_W20   2512   // 9
#define CP_W10   2521   // 9
#define CP_SC    2530   // g2_0, b2_0, g1_0, b1_0, K
#define CP_SIZE  2560

// ---------------- prep: reorder / fold weights into const pack ----------------
__global__ __launch_bounds__(256) void k_prep(
    const float* __restrict__ s0_w2, const float* __restrict__ s0_g2, const float* __restrict__ s0_b2,
    const float* __restrict__ s0_w1, const float* __restrict__ s0_g1, const float* __restrict__ s0_b1,
    const float* __restrict__ s0_wp, const float* __restrict__ s0_gp, const float* __restrict__ s0_bp,
    const float* __restrict__ s1_w2, const float* __restrict__ s1_g2, const float* __restrict__ s1_b2,
    const float* __restrict__ s1_w1, const float* __restrict__ s1_g1, const float* __restrict__ s1_b1,
    const float* __restrict__ s1_wp, const float* __restrict__ s1_gp, const float* __restrict__ s1_bp,
    float* __restrict__ cp)
{
  const int t = threadIdx.x;
  for (int e = t; e < 2304; e += 256){
    int co = e / 144, r = e % 144, cin = r / 9, n = r % 9;
    cp[CP_W2L + (cin*9 + n)*16 + co] = s1_w2[e];
  }
  const float gp1 = s1_gp[0];
  for (int e = t; e < 144; e += 256){
    int ci = e / 9, n = e % 9;
    float s = 0.f;
    for (int co = 0; co < 16; co++)
      s += gp1 * s1_wp[co] * s1_g1[co] * s1_w1[(co*16 + ci)*9 + n];
    cp[CP_WEFF + e] = s;
  }
  if (t < 16){
    cp[CP_A + t]  = s0_gp[t] * s0_wp[t];
    cp[CP_B + t]  = s0_bp[t];
    cp[CP_G2 + t] = s1_g2[t];
    cp[CP_B2 + t] = s1_b2[t];
  }
  if (t < 9){ cp[CP_W20 + t] = s0_w2[t]; cp[CP_W10 + t] = s0_w1[t]; }
  if (t == 0){
    cp[CP_SC + 0] = s0_g2[0]; cp[CP_SC + 1] = s0_b2[0];
    cp[CP_SC + 2] = s0_g1[0]; cp[CP_SC + 3] = s0_b1[0];
    float kk = 0.f;
    for (int co = 0; co < 16; co++) kk += s1_wp[co] * s1_b1[co];
    cp[CP_SC + 4] = gp1 * kk + s1_bp[0];
  }
}

// ---------------- per-(image,pixel) channel means ----------------
__global__ __launch_bounds__(256) void k_means(
    const float* __restrict__ spt, const float* __restrict__ qry,
    float* __restrict__ sptm, float* __restrict__ qrym)
{
  const int idx = blockIdx.x * 256 + threadIdx.x;
  if (idx >= 500 + NQT * NPIX) return;
  const float* src; float* dst;
  if (idx < 500){
    int n = idx / NPIX, ij = idx % NPIX;
    src = spt + (size_t)n * CCH * NPIX + ij; dst = sptm + idx;
  } else {
    int k = idx - 500; int n = k / NPIX, ij = k % NPIX;
    src = qry + (size_t)n * CCH * NPIX + ij; dst = qrym + k;
  }
  float s = 0.f;
  for (int c = 0; c < CCH; c++) s += src[(size_t)c * NPIX];
  *dst = s * (1.f / CCH);
}

// ---------------- feat: 1x1 conv 640->64 + affine + relu + L2-normalize ----------------
// 128 threads: thread = (o = t>>1, half = t&1), acc[50] pixels, LDS c-tiles with
// aligned float4 reads (half starts at 52-float offset -> 208B, 16B aligned).
__global__ __launch_bounds__(128) void k_feat(
    const float* __restrict__ spt, const float* __restrict__ qry,
    const float* __restrict__ sptm, const float* __restrict__ qrym,
    const float* __restrict__ W, const float* __restrict__ gg, const float* __restrict__ bb,
    float* __restrict__ s_feat, float* __restrict__ q_feat)
{
  __shared__ __align__(16) float tile[16*104];
  __shared__ float y[6400];
  __shared__ float invn[100];
  const int n = blockIdx.x;
  const float* x; const float* mp; float* out;
  if (n < 5){ x = spt + (size_t)n * 64000; mp = sptm + n * 100; out = s_feat + (size_t)n * 6400; }
  else { x = qry + (size_t)(n-5) * 64000; mp = qrym + (size_t)(n-5) * 100; out = q_feat + (size_t)(n-5) * 6400; }
  const int t = threadIdx.x;
  const int o = t >> 1, half = t & 1;
  float acc[50];
  #pragma unroll
  for (int k = 0; k < 50; k++) acc[k] = 0.f;
  float wsum = 0.f;
  const float* wr = W + (size_t)o * 640;
  for (int c0 = 0; c0 < 640; c0 += 16){
    __syncthreads();
    for (int e = t; e < 1600; e += 128){
      int cc = e / 100, pix = e % 100;
      tile[cc*104 + (pix < 50 ? pix : pix + 2)] = x[(size_t)(c0+cc)*100 + pix];
    }
    __syncthreads();
    #pragma unroll
    for (int cc = 0; cc < 16; cc++){
      const float wv = wr[c0 + cc];
      wsum += wv;
      const float* row = &tile[cc*104 + half*52];
      #pragma unroll
      for (int kk = 0; kk < 12; kk++){
        const float4 v4 = ((const float4*)row)[kk];
        acc[kk*4+0] += wv*v4.x; acc[kk*4+1] += wv*v4.y;
        acc[kk*4+2] += wv*v4.z; acc[kk*4+3] += wv*v4.w;
      }
      acc[48] += wv*row[48]; acc[49] += wv*row[49];
    }
  }
  const float go = gg[o], bo = bb[o];
  #pragma unroll
  for (int k = 0; k < 50; k++){
    const int pix = half*50 + k;
    float v = go * (acc[k] - wsum * mp[pix]) + bo;
    y[o*100 + pix] = fmaxf(v, 0.f);
  }
  __syncthreads();
  if (t < 100){
    float s = 0.f;
    #pragma unroll
    for (int o2 = 0; o2 < 64; o2++){ float v = y[o2*100 + t]; s += v*v; }
    invn[t] = 1.f / fmaxf(sqrtf(s), 1e-8f);
  }
  __syncthreads();
  for (int e = t; e < 6400; e += 128) out[e] = y[e] * invn[e % 100];
}

// ---------------- k_z: corr + SepConv4d layer0 -> z (f16) ----------------
__global__ __launch_bounds__(128) void k_z(
    const float* __restrict__ s_feat, const float* __restrict__ q_feat,
    const float* __restrict__ cp, __half* __restrict__ z)
{
  __shared__ float buf[NPIX * PADB];            // [uv][hw] padded
  __shared__ __align__(16) float t1s[3200];     // corr staging tiles
  const int pair = blockIdx.x;
  const int q = pair / WAYT, w = pair % WAYT;
  const int t = threadIdx.x;

  float col[100];
  #pragma unroll
  for (int i = 0; i < 100; i++) col[i] = 0.f;

  for (int ct = 0; ct < 4; ct++){
    __syncthreads();
    for (int e = t; e < 1600; e += 128){
      t1s[e]        = s_feat[w*6400 + ct*1600 + e];
      t1s[1600 + e] = q_feat[(size_t)q*6400 + ct*1600 + e];
    }
    __syncthreads();
    if (t < 100){
      float qr[16];
      #pragma unroll
      for (int cc = 0; cc < 16; cc++) qr[cc] = t1s[1600 + cc*100 + t];
      #pragma unroll
      for (int u4 = 0; u4 < 25; u4++){
        float a0=0.f, a1=0.f, a2=0.f, a3=0.f;
        #pragma unroll
        for (int cc = 0; cc < 16; cc++){
          const float4 sv = *(const float4*)&t1s[cc*100 + u4*4];
          a0 += sv.x*qr[cc]; a1 += sv.y*qr[cc];
          a2 += sv.z*qr[cc]; a3 += sv.w*qr[cc];
        }
        col[u4*4+0]+=a0; col[u4*4+1]+=a1; col[u4*4+2]+=a2; col[u4*4+3]+=a3;
      }
    }
  }

  // layer0 conv over (u,v) + affine + relu
  if (t < 100){
    float w20r[9];
    #pragma unroll
    for (int i = 0; i < 9; i++) w20r[i] = cp[CP_W20 + i];
    const float g20 = cp[CP_SC+0], b20 = cp[CP_SC+1];
    #pragma unroll
    for (int u = 0; u < 10; u++){
      #pragma unroll
      for (int v = 0; v < 10; v++){
        float o = 0.f;
        #pragma unroll
        for (int du = 0; du < 3; du++){
          const int uu = u + du - 1;
          if (uu < 0 || uu > 9) continue;
          #pragma unroll
          for (int dv = 0; dv < 3; dv++){
            const int vv = v + dv - 1;
            if (vv < 0 || vv > 9) continue;
            o += w20r[du*3+dv] * col[uu*10+vv];
          }
        }
        o = g20*o + b20;
        buf[(u*10+v)*PADB + t] = fmaxf(o, 0.f);
      }
    }
  }
  __syncthreads();

  // layer0 conv over (h,w) + affine (row t, in place)
  if (t < 100){
    float row[100];
    #pragma unroll
    for (int k = 0; k < 100; k++) row[k] = buf[t*PADB + k];
    float w10r[9];
    #pragma unroll
    for (int i = 0; i < 9; i++) w10r[i] = cp[CP_W10 + i];
    const float g10 = cp[CP_SC+2], b10 = cp[CP_SC+3];
    #pragma unroll
    for (int h = 0; h < 10; h++){
      #pragma unroll
      for (int ww = 0; ww < 10; ww++){
        float o = 0.f;
        #pragma unroll
        for (int dh = 0; dh < 3; dh++){
          const int hh2 = h + dh - 1;
          if (hh2 < 0 || hh2 > 9) continue;
          #pragma unroll
          for (int dw = 0; dw < 3; dw++){
            const int ww2 = ww + dw - 1;
            if (ww2 < 0 || ww2 > 9) continue;
            o += w10r[dh*3+dw] * row[hh2*10+ww2];
          }
        }
        buf[t*PADB + h*10+ww] = g10*o + b10;
      }
    }
  }
  __syncthreads();
  for (int e = t; e < 10000; e += 128)
    z[(size_t)pair*10000 + e] = __float2half(buf[(e/100)*PADB + e%100]);
}

// ---------------- k_l1: layer1 for one (pair, u-row); grid (10, 750) ----------------
__global__ __launch_bounds__(128) void k_l1(
    const __half* __restrict__ z, const float* __restrict__ cp, __half* __restrict__ Fh)
{
  __shared__ float zr[3000];                    // z rows u-1..u+1: [r][v][hw]
  __shared__ __align__(16) float2 t1s[1600];    // t1 for 2 cols: [co][hw] -> (colA,colB)
  const int u = blockIdx.x, pair = blockIdx.y;
  const int t = threadIdx.x;

  for (int e = t; e < 3000; e += 128){
    const int g = (u-1)*1000 + e;
    if (g >= 0 && g < 10000) zr[e] = __half2float(z[(size_t)pair*10000 + g]);
  }
  __syncthreads();

  const float Kc = cp[CP_SC+4];
  const int hT = t / 10, wT = t % 10;

  #pragma unroll 1
  for (int v0x = 0; v0x < 5; v0x++){
    const int v0 = 2*v0x;
    if (t < 100){
      float a0[16], a1[16];
      #pragma unroll
      for (int i = 0; i < 16; i++){ a0[i]=0.f; a1[i]=0.f; }
      #pragma unroll
      for (int du = 0; du < 3; du++){
        const int ur = u + du - 1;
        if (ur < 0 || ur > 9) continue;
        float z4[4]; bool zok[4];
        #pragma unroll
        for (int k = 0; k < 4; k++){
          const int vc = v0 - 1 + k;
          zok[k] = (vc >= 0 && vc < 10);
          z4[k] = zok[k] ? zr[du*1000 + vc*100 + t] : 0.f;
        }
        #pragma unroll 2
        for (int cin = 0; cin < 16; cin++){
          const float A = cp[CP_A + cin], B = cp[CP_B + cin];
          float r4[4];
          #pragma unroll
          for (int k = 0; k < 4; k++)
            r4[k] = zok[k] ? fmaxf(A*z4[k] + B, 0.f) : 0.f;  // conv pads the relu'd field with 0
          #pragma unroll
          for (int dv = 0; dv < 3; dv++){
            const float4* wp4 = (const float4*)&cp[CP_W2L + (cin*9 + du*3 + dv)*16];
            const float ra = r4[dv], rb = r4[dv+1];
            #pragma unroll
            for (int c4 = 0; c4 < 4; c4++){
              const float4 wq = wp4[c4];
              a0[c4*4+0] += wq.x*ra; a1[c4*4+0] += wq.x*rb;
              a0[c4*4+1] += wq.y*ra; a1[c4*4+1] += wq.y*rb;
              a0[c4*4+2] += wq.z*ra; a1[c4*4+2] += wq.z*rb;
              a0[c4*4+3] += wq.w*ra; a1[c4*4+3] += wq.w*rb;
            }
          }
        }
      }
      #pragma unroll
      for (int co = 0; co < 16; co++){
        const float g2 = cp[CP_G2 + co], b2 = cp[CP_B2 + co];
        t1s[co*100 + t] = make_float2(fmaxf(g2*a0[co] + b2, 0.f),
                                      fmaxf(g2*a1[co] + b2, 0.f));
      }
    }
    __syncthreads();
    if (t < 100){
      float o0 = Kc, o1 = Kc;
      #pragma unroll 4
      for (int ci = 0; ci < 16; ci++){
        #pragma unroll
        for (int dh = 0; dh < 3; dh++){
          const int hh2 = hT + dh - 1;
          if (hh2 < 0 || hh2 > 9) continue;
          #pragma unroll
          for (int dw = 0; dw < 3; dw++){
            const int ww2 = wT + dw - 1;
            if (ww2 < 0 || ww2 > 9) continue;
            const float we = cp[CP_WEFF + ci*9 + dh*3 + dw];
            const float2 v = t1s[ci*100 + hh2*10 + ww2];
            o0 += we*v.x; o1 += we*v.y;
          }
        }
      }
      Fh[(size_t)pair*10000 + (u*10 + v0    )*100 + t] = __float2half(o0);
      Fh[(size_t)pair*10000 + (u*10 + v0 + 1)*100 + t] = __float2half(o1);
    }
    __syncthreads();
  }
}

// ---------------- gnorm + softmax attention + pooled cosine ----------------
__global__ __launch_bounds__(128) void k_attn(
    const __half* __restrict__ Fh, const float* __restrict__ spt,
    const float* __restrict__ qry, const float* __restrict__ sptm,
    const float* __restrict__ qrym, float* __restrict__ out)
{
  __shared__ float buf[NPIX * PADB];   // F plane, later reused as [64][101] tiles
  __shared__ float isc[100], ccs[100], isr[100], ccr[100];
  __shared__ float av[200];
  __shared__ float prodA[100], prodB[100];
  __shared__ float sc2[2];
  __shared__ float red[6];
  const int pair = blockIdx.x;
  const int q = pair / WAYT, w = pair % WAYT;
  const int t = threadIdx.x;
  const float L2T = 1.4426950408889634f * 0.2f;   // log2(e)/TEMP_ATTN

  for (int e = t; e < 10000; e += 128)
    buf[(e/100)*PADB + (e%100)] = __half2float(Fh[(size_t)pair*10000 + e]);
  __syncthreads();

  if (t < 100){
    // column stats (over uv) for hw = t
    float s = 0.f;
    for (int uv = 0; uv < 100; uv++) s += buf[uv*PADB + t];
    const float m = s * 0.01f;
    float ss = 0.f;
    for (int uv = 0; uv < 100; uv++){ const float d = buf[uv*PADB + t] - m; ss += d*d; }
    const float is2 = rsqrtf(ss * (1.f/99.f) + 1e-5f) * L2T;
    float S = 0.f;   // |(x-m)/sigma| <= sqrt(99) -> arg <= 2.87, no overflow: skip max pass
    for (int uv = 0; uv < 100; uv++) S += exp2f((buf[uv*PADB + t] - m) * is2);
    isc[t] = is2; ccs[t] = m*is2 + log2f(S);
    // row stats (over hw) for uv = t
    float s2 = 0.f;
    for (int k = 0; k < 100; k++) s2 += buf[t*PADB + k];
    const float m2 = s2 * 0.01f;
    float ss2 = 0.f;
    for (int k = 0; k < 100; k++){ const float d = buf[t*PADB + k] - m2; ss2 += d*d; }
    const float is2r = rsqrtf(ss2 * (1.f/99.f) + 1e-5f) * L2T;
    float Sr = 0.f;
    for (int k = 0; k < 100; k++) Sr += exp2f((buf[t*PADB + k] - m2) * is2r);
    isr[t] = is2r; ccr[t] = m2*is2r + log2f(Sr);
  }
  __syncthreads();
  if (t < 100){
    float a = 0.f;   // a_s[uv=t]
    for (int hw = 0; hw < 100; hw++)
      a += exp2f(buf[t*PADB + hw] * isc[hw] - ccs[hw]);
    av[t] = a;
    float b = 0.f;   // a_q[hw=t]
    for (int uv = 0; uv < 100; uv++)
      b += exp2f(buf[uv*PADB + t] * isr[uv] - ccr[uv]);
    av[100 + t] = b;
  }
  __syncthreads();
  if (t < 100){
    prodA[t] = av[t]       * sptm[w*100 + t];
    prodB[t] = av[100 + t] * qrym[q*100 + t];
  }
  __syncthreads();
  if (t == 0){ float s = 0.f; for (int i = 0; i < 100; i++) s += prodA[i]; sc2[0] = s; }
  if (t == 1){ float s = 0.f; for (int i = 0; i < 100; i++) s += prodB[i]; sc2[1] = s; }
  __syncthreads();

  // pooled prototypes + cosine, LDS-tiled (64 channels x 100 pix per tile)
  float d0 = 0.f, d1 = 0.f, d2 = 0.f;
  const int cc = t >> 1, half = t & 1;
  const float sA = sc2[0], qA = sc2[1];
  for (int c0 = 0; c0 < 640; c0 += 64){
    __syncthreads();
    for (int e = t; e < 6400; e += 128)
      buf[(e/100)*PADB + (e%100)] = spt[(size_t)w*64000 + (size_t)(c0 + e/100)*100 + e%100];
    __syncthreads();
    float a = 0.f;
    #pragma unroll
    for (int j = 0; j < 50; j++) a += av[half*50 + j] * buf[cc*PADB + half*50 + j];
    a += __shfl_xor(a, 1);
    const float sp = 0.01f * (a - sA);
    __syncthreads();
    for (int e = t; e < 6400; e += 128)
      buf[(e/100)*PADB + (e%100)] = qry[(size_t)q*64000 + (size_t)(c0 + e/100)*100 + e%100];
    __syncthreads();
    float b = 0.f;
    #pragma unroll
    for (int j = 0; j < 50; j++) b += av[100 + half*50 + j] * buf[cc*PADB + half*50 + j];
    b += __shfl_xor(b, 1);
    const float qp = 0.01f * (b - qA);
    d0 += sp*qp; d1 += sp*sp; d2 += qp*qp;
  }
  // lane pairs hold duplicates -> sums are 2x; halve at the end
  #pragma unroll
  for (int msk = 1; msk < 64; msk <<= 1){
    d0 += __shfl_xor(d0, msk); d1 += __shfl_xor(d1, msk); d2 += __shfl_xor(d2, msk);
  }
  if ((t & 63) == 0){
    const int wid = t >> 6;
    red[wid*3+0] = d0; red[wid*3+1] = d1; red[wid*3+2] = d2;
  }
  __syncthreads();
  if (t == 0){
    const float e0 = 0.5f*(red[0] + red[3]);
    const float e1 = 0.5f*(red[1] + red[4]);
    const float e2 = 0.5f*(red[2] + red[5]);
    const float den = fmaxf(sqrtf(e1), 1e-8f) * fmaxf(sqrtf(e2), 1e-8f);
    out[pair] = (e0 / den) * 5.0f;   // / TEMP(0.2)
  }
}

extern "C" void kernel_launch(void* const* d_in, const int* in_sizes, int n_in,
                              void* d_out, int out_size, void* d_ws, size_t ws_size,
                              hipStream_t stream)
{
  (void)in_sizes; (void)n_in; (void)out_size; (void)ws_size;
  const float* spt = (const float*)d_in[0];
  const float* qry = (const float*)d_in[1];
  const float* Wc  = (const float*)d_in[2];
  const float* gc  = (const float*)d_in[3];
  const float* bc  = (const float*)d_in[4];

  float* ws    = (float*)d_ws;
  float* cp    = ws;                  // 2560
  float* sptm  = ws + 2560;           // 512
  float* qrym  = ws + 3072;           // 15104
  float* sfeat = ws + 18176;          // 32000
  float* qfeat = ws + 50176;          // 960000
  __half* z    = (__half*)(ws + 1010176);            // 7.5M halfs (15 MB)
  __half* Fh   = (__half*)(ws + 1010176 + 3750000);  // 7.5M halfs (15 MB), end ~34 MB

  k_prep<<<1, 256, 0, stream>>>(
      (const float*)d_in[5],  (const float*)d_in[6],  (const float*)d_in[7],
      (const float*)d_in[8],  (const float*)d_in[9],  (const float*)d_in[10],
      (const float*)d_in[11], (const float*)d_in[12], (const float*)d_in[13],
      (const float*)d_in[14], (const float*)d_in[15], (const float*)d_in[16],
      (const float*)d_in[17], (const float*)d_in[18], (const float*)d_in[19],
      (const float*)d_in[20], (const float*)d_in[21], (const float*)d_in[22],
      cp);
  k_means<<<(500 + NQT*NPIX + 255)/256, 256, 0, stream>>>(spt, qry, sptm, qrym);
  k_feat<<<155, 128, 0, stream>>>(spt, qry, sptm, qrym, Wc, gc, bc, sfeat, qfeat);
  k_z<<<NQT*WAYT, 128, 0, stream>>>(sfeat, qfeat, cp, z);
  {
    dim3 grid(10, NQT*WAYT);
    k_l1<<<grid, 128, 0, stream>>>(z, cp, Fh);
  }
  k_attn<<<NQT*WAYT, 128, 0, stream>>>(Fh, spt, qry, sptm, qrym, (float*)d_out);
}

// Round 3
// 532.166 us; speedup vs baseline: 3.6608x; 2.1375x over previous
//
#include <hip/hip_runtime.h>
#include <cstdint>
#include <cstddef>

#define NQT   150
#define WAYT  5
#define CCH   640

typedef _Float16 f16;
typedef _Float16 f16x2 __attribute__((ext_vector_type(2)));
typedef _Float16 f16x4 __attribute__((ext_vector_type(4)));
typedef _Float16 f16x8 __attribute__((ext_vector_type(8)));
typedef float    f32x4 __attribute__((ext_vector_type(4)));

// const-pack offsets (floats)
#define CP_A     0      // 16  gp*wp per cin
#define CP_B     16     // 16  bp per cin
#define CP_G2    32     // 16
#define CP_B2    48     // 16
#define CP_W20   64     // 9
#define CP_W10   73     // 9
#define CP_SC    82     // g2_0, b2_0, g1_0, b1_0, K

// ---------------- prep ----------------
__global__ __launch_bounds__(256) void k_prep(
    const float* __restrict__ s0_w2, const float* __restrict__ s0_g2, const float* __restrict__ s0_b2,
    const float* __restrict__ s0_w1, const float* __restrict__ s0_g1, const float* __restrict__ s0_b1,
    const float* __restrict__ s0_wp, const float* __restrict__ s0_gp, const float* __restrict__ s0_bp,
    const float* __restrict__ s1_w2, const float* __restrict__ s1_g2, const float* __restrict__ s1_b2,
    const float* __restrict__ s1_w1, const float* __restrict__ s1_g1, const float* __restrict__ s1_b1,
    const float* __restrict__ s1_wp, const float* __restrict__ s1_gp, const float* __restrict__ s1_bp,
    float* __restrict__ cp, f16* __restrict__ Apack, f16* __restrict__ weffh)
{
  const int t = threadIdx.x;
  // Apack: [p(5)][lane(64)][j(8)] : A-fragment for mfma_16x16x32_f16, taps paired along K
  for (int e = t; e < 2560; e += 256){
    int p = e / 512, r = e % 512, l = r / 8, j = r % 8;
    int kb = l >> 4;                 // 0..3
    int tap = 2*p + (kb >> 1);       // 0..9
    int cin = (kb & 1)*8 + j;
    int co = l & 15;
    float v = 0.f;
    if (tap <= 8){
      int du = tap / 3, dv = tap % 3;
      v = s1_w2[((co*16 + cin)*3 + du)*3 + dv];
    }
    Apack[e] = (f16)v;
  }
  const float gp1 = s1_gp[0];
  // weffh[tap][ci]
  for (int e = t; e < 144; e += 256){
    int tap = e / 16, ci = e % 16;
    float s = 0.f;
    for (int co = 0; co < 16; co++)
      s += gp1 * s1_wp[co] * s1_g1[co] * s1_w1[(co*16 + ci)*9 + tap];
    weffh[e] = (f16)s;
  }
  if (t < 16){
    cp[CP_A + t]  = s0_gp[t] * s0_wp[t];
    cp[CP_B + t]  = s0_bp[t];
    cp[CP_G2 + t] = s1_g2[t];
    cp[CP_B2 + t] = s1_b2[t];
  }
  if (t < 9){ cp[CP_W20 + t] = s0_w2[t]; cp[CP_W10 + t] = s0_w1[t]; }
  if (t == 0){
    cp[CP_SC + 0] = s0_g2[0]; cp[CP_SC + 1] = s0_b2[0];
    cp[CP_SC + 2] = s0_g1[0]; cp[CP_SC + 3] = s0_b1[0];
    float kk = 0.f;
    for (int co = 0; co < 16; co++) kk += s1_wp[co] * s1_b1[co];
    cp[CP_SC + 4] = gp1 * kk + s1_bp[0];
  }
}

// ---------------- per-(image,pixel) channel means ----------------
__global__ __launch_bounds__(256) void k_means(
    const float* __restrict__ spt, const float* __restrict__ qry,
    float* __restrict__ sptm, float* __restrict__ qrym)
{
  const int idx = blockIdx.x * 256 + threadIdx.x;
  if (idx >= 500 + NQT * 100) return;
  const float* src; float* dst;
  if (idx < 500){
    int n = idx / 100, ij = idx % 100;
    src = spt + (size_t)n * CCH * 100 + ij; dst = sptm + idx;
  } else {
    int k = idx - 500; int n = k / 100, ij = k % 100;
    src = qry + (size_t)n * CCH * 100 + ij; dst = qrym + k;
  }
  float s = 0.f;
  for (int c = 0; c < CCH; c++) s += src[(size_t)c * 100];
  *dst = s * (1.f / CCH);
}

// ---------------- feat: 1x1 conv 640->64 + affine + relu + L2-norm -> f16 [112][64] ----------------
__global__ __launch_bounds__(256) void k_feat(
    const float* __restrict__ spt, const float* __restrict__ qry,
    const float* __restrict__ sptm, const float* __restrict__ qrym,
    const float* __restrict__ W, const float* __restrict__ gg, const float* __restrict__ bb,
    f16* __restrict__ s16, f16* __restrict__ q16)
{
  __shared__ __align__(16) float tile[16*116];   // row stride 116 (464B) kills bank aliasing
  __shared__ float y[6400];
  __shared__ float invn[100];
  const int n = blockIdx.x;
  const float* x; const float* mp; f16* out16;
  if (n < 5){ x = spt + (size_t)n * 64000; mp = sptm + n * 100; out16 = s16 + (size_t)n * 7168; }
  else { x = qry + (size_t)(n-5) * 64000; mp = qrym + (size_t)(n-5) * 100; out16 = q16 + (size_t)(n-5) * 7168; }
  const int t = threadIdx.x;
  const int o = t >> 2, qq = t & 3;
  float acc[25];
  #pragma unroll
  for (int k = 0; k < 25; k++) acc[k] = 0.f;
  float wsum = 0.f;
  const float* wr = W + (size_t)o * 640;
  for (int c0 = 0; c0 < 640; c0 += 16){
    __syncthreads();
    for (int e = t; e < 1600; e += 256){
      int cc = e / 100, pix = e % 100;
      tile[cc*116 + (pix/25)*28 + pix%25] = x[(size_t)(c0+cc)*100 + pix];
    }
    __syncthreads();
    #pragma unroll
    for (int cc = 0; cc < 16; cc++){
      const float wv = wr[c0 + cc];
      wsum += wv;
      const float* row = &tile[cc*116 + qq*28];
      #pragma unroll
      for (int kk = 0; kk < 6; kk++){
        const float4 v4 = ((const float4*)row)[kk];
        acc[kk*4+0] += wv*v4.x; acc[kk*4+1] += wv*v4.y;
        acc[kk*4+2] += wv*v4.z; acc[kk*4+3] += wv*v4.w;
      }
      acc[24] += wv*row[24];
    }
  }
  const float go = gg[o], bo = bb[o];
  #pragma unroll
  for (int k = 0; k < 25; k++){
    const int pix = qq*25 + k;
    float v = go * (acc[k] - wsum * mp[pix]) + bo;
    y[o*100 + pix] = fmaxf(v, 0.f);
  }
  __syncthreads();
  if (t < 100){
    float s = 0.f;
    #pragma unroll
    for (int o2 = 0; o2 < 64; o2++){ float v = y[o2*100 + t]; s += v*v; }
    invn[t] = 1.f / fmaxf(sqrtf(s), 1e-8f);
  }
  __syncthreads();
  for (int e = t; e < 7168; e += 256){
    int pix = e >> 6, o2 = e & 63;
    out16[e] = (pix < 100) ? (f16)(y[o2*100 + pix] * invn[pix]) : (f16)0.f;
  }
}

// ---------------- k_z: MFMA corr + SepConv4d layer0 -> z (f16) ----------------
__global__ __launch_bounds__(256) void k_z(
    const f16* __restrict__ s16, const f16* __restrict__ q16,
    const float* __restrict__ cp, f16* __restrict__ z)
{
  __shared__ float cb[100*101 + 4];
  const int pair = blockIdx.x;
  const int q = pair / WAYT, w = pair % WAYT;
  const int t = threadIdx.x;
  const int l = t & 63, wid = t >> 6;
  const int r16 = l & 15, kb = (l >> 4) & 3;

  const f16* sbase = s16 + (size_t)w * 7168;
  const f16* qbase = q16 + (size_t)q * 7168;

  // corr: C[uv][hw] = sum_c s[uv][c]*q[hw][c]  (feats pixel-major [112][64])
  for (int mi = 0; mi < 2; mi++){
    const int mt = wid + mi*4;
    if (mt > 6) break;
    const f16x8 a0 = *(const f16x8*)(sbase + (mt*16 + r16)*64 + kb*8);
    const f16x8 a1 = *(const f16x8*)(sbase + (mt*16 + r16)*64 + 32 + kb*8);
    for (int nt = 0; nt < 7; nt++){
      const f16x8 b0 = *(const f16x8*)(qbase + (nt*16 + r16)*64 + kb*8);
      const f16x8 b1 = *(const f16x8*)(qbase + (nt*16 + r16)*64 + 32 + kb*8);
      f32x4 acc = {0.f,0.f,0.f,0.f};
      acc = __builtin_amdgcn_mfma_f32_16x16x32_f16(a0, b0, acc, 0, 0, 0);
      acc = __builtin_amdgcn_mfma_f32_16x16x32_f16(a1, b1, acc, 0, 0, 0);
      const int hw = nt*16 + r16;
      if (hw < 100){
        #pragma unroll
        for (int r = 0; r < 4; r++){
          const int uv = mt*16 + kb*4 + r;
          if (uv < 100) cb[uv*101 + hw] = acc[r];
        }
      }
    }
  }
  __syncthreads();

  // layer0 conv over (u,v) + affine + relu
  const float g20 = cp[CP_SC+0], b20 = cp[CP_SC+1];
  float rr[50];
  const int lineB = t & 127, halfB = t >> 7;
  if (lineB < 100){
    const int hw = lineB;
    #pragma unroll
    for (int i = 0; i < 50; i++){
      const int u = halfB*5 + i/10, v = i % 10;
      float o = 0.f;
      #pragma unroll
      for (int du = 0; du < 3; du++){
        const int uu = u + du - 1;
        if (uu < 0 || uu > 9) continue;
        #pragma unroll
        for (int dv = 0; dv < 3; dv++){
          const int vv = v + dv - 1;
          if (vv < 0 || vv > 9) continue;
          o += cp[CP_W20 + du*3+dv] * cb[(uu*10+vv)*101 + hw];
        }
      }
      rr[i] = fmaxf(g20*o + b20, 0.f);
    }
  }
  __syncthreads();
  if (lineB < 100){
    #pragma unroll
    for (int i = 0; i < 50; i++)
      cb[(halfB*50 + i)*101 + lineB] = rr[i];
  }
  __syncthreads();

  // layer0 conv over (h,w) + affine -> z
  const float g10 = cp[CP_SC+2], b10 = cp[CP_SC+3];
  if (lineB < 100){
    const int uv = lineB, hwhalf = halfB;
    #pragma unroll
    for (int k = 0; k < 50; k++){
      const int h = hwhalf*5 + k/10, ww = k % 10;
      float o = 0.f;
      #pragma unroll
      for (int dh = 0; dh < 3; dh++){
        const int hh = h + dh - 1;
        if (hh < 0 || hh > 9) continue;
        #pragma unroll
        for (int dw = 0; dw < 3; dw++){
          const int w2 = ww + dw - 1;
          if (w2 < 0 || w2 > 9) continue;
          o += cp[CP_W10 + dh*3+dw] * cb[uv*101 + hh*10 + w2];
        }
      }
      z[(size_t)pair*10000 + uv*100 + hwhalf*50 + k] = (f16)(g10*o + b10);
    }
  }
}

// ---------------- k_l1: layer1 via MFMA; grid (10 u-rows, 750 pairs) ----------------
__global__ __launch_bounds__(256) void k_l1(
    const f16* __restrict__ z, const float* __restrict__ cp,
    const f16* __restrict__ Apack, const f16* __restrict__ weffh, f16* __restrict__ F)
{
  // t1L [1016 cols][20 f16] (40B rows); z3 [3][1216] f32 aliased under it (barrier-separated)
  __shared__ __align__(16) char sm[512 + 1016*40];
  float* z3 = (float*)(sm + 512);
  f16*  t1L = (f16*)(sm + 512);
  const int u = blockIdx.x, pair = blockIdx.y;
  const int t = threadIdx.x, l = t & 63, wid = t >> 6;
  const int r16 = l & 15, kb = (l >> 4) & 3;
  const int khi = kb & 1, half = kb >> 1;

  // load z rows u-1..u+1 (cols 100..1099 of each 1216-row; pads masked later)
  for (int e = t; e < 3000; e += 256){
    const int du = (e >= 2000) ? 2 : (e >= 1000 ? 1 : 0);
    const int col = e - du*1000;
    const int ur = u + du - 1;
    if (ur >= 0 && ur <= 9)
      z3[du*1216 + 100 + col] = (float)z[(size_t)pair*10000 + ur*1000 + col];
  }

  // per-lane constants
  float Ac[8], Bc[8];
  {
    const float4 a4a = ((const float4*)(cp + CP_A))[khi*2];
    const float4 a4b = ((const float4*)(cp + CP_A))[khi*2+1];
    const float4 b4a = ((const float4*)(cp + CP_B))[khi*2];
    const float4 b4b = ((const float4*)(cp + CP_B))[khi*2+1];
    Ac[0]=a4a.x;Ac[1]=a4a.y;Ac[2]=a4a.z;Ac[3]=a4a.w;Ac[4]=a4b.x;Ac[5]=a4b.y;Ac[6]=a4b.z;Ac[7]=a4b.w;
    Bc[0]=b4a.x;Bc[1]=b4a.y;Bc[2]=b4a.z;Bc[3]=b4a.w;Bc[4]=b4b.x;Bc[5]=b4b.y;Bc[6]=b4b.z;Bc[7]=b4b.w;
  }
  f16x8 af[5];
  #pragma unroll
  for (int p = 0; p < 5; p++) af[p] = ((const f16x8*)Apack)[p*64 + l];
  int zoff[5], dvm[5];
  #pragma unroll
  for (int p = 0; p < 5; p++){
    const int tap = 2*p + half;
    const int du = (tap <= 8) ? tap/3 : 2;
    const int dv = (tap <= 8) ? tap%3 : 0;
    const bool ok = (tap <= 8) && (u + du - 1 >= 0) && (u + du - 1 <= 9);
    zoff[p] = du*1216 + dv*100;
    dvm[p]  = ok ? (dv - 1) : 1000;
  }
  __syncthreads();

  // stage 1: C[16co][1008 cols] = sum_taps W_tap * relu(A*z+B), MFMA K=32 (2 taps)
  f32x4 accA[16];
  const int cwb = wid * 256;
  #pragma unroll
  for (int i = 0; i < 16; i++){
    const int cbase = cwb + i*16;
    if (cbase >= 1008){ accA[i] = (f32x4){0.f,0.f,0.f,0.f}; continue; }
    const int c = cbase + r16;
    const int v = (c * 5243) >> 19;
    f32x4 acc = {0.f,0.f,0.f,0.f};
    #pragma unroll
    for (int p = 0; p < 5; p++){
      const float zv = z3[zoff[p] + c];
      const bool ok = ((unsigned)(v + dvm[p])) <= 9u;
      f16x8 bf;
      #pragma unroll
      for (int j = 0; j < 8; j++){
        const float rj = fmaxf(fmaf(Ac[j], zv, Bc[j]), 0.f);
        bf[j] = ok ? (f16)rj : (f16)0.f;
      }
      acc = __builtin_amdgcn_mfma_f32_16x16x32_f16(af[p], bf, acc, 0, 0, 0);
    }
    accA[i] = acc;
  }
  __syncthreads();   // all z3 reads done; t1L may now overwrite

  // epilogue: t1 = relu(g2*C + b2) -> t1L f16 [col][20]
  {
    const float4 g4 = ((const float4*)(cp + CP_G2))[kb];
    const float4 b4 = ((const float4*)(cp + CP_B2))[kb];
    const float gv[4] = {g4.x, g4.y, g4.z, g4.w};
    const float bv[4] = {b4.x, b4.y, b4.z, b4.w};
    #pragma unroll
    for (int i = 0; i < 16; i++){
      const int c = cwb + i*16 + r16;
      if (cwb + i*16 >= 1008) continue;
      f16x4 hv;
      #pragma unroll
      for (int r = 0; r < 4; r++)
        hv[r] = (f16)fmaxf(fmaf(gv[r], accA[i][r], bv[r]), 0.f);
      *(f16x4*)(t1L + c*20 + kb*4) = hv;
    }
  }
  __syncthreads();

  // stage 2: F[col] = K + sum_{ci,taphw} weff * t1  (v_dot2_f32_f16)
  const float Kc = cp[CP_SC+4];
  #pragma unroll 1
  for (int oo = 0; oo < 4; oo++){
    const int c = t + oo*256;
    if (c >= 1000) continue;
    const int hw = c - ((c * 5243) >> 19) * 100;
    const int h = (hw * 205) >> 11, w2 = hw - h*10;
    float o = Kc;
    #pragma unroll
    for (int dh = 0; dh < 3; dh++){
      const int hh = h + dh - 1;
      const bool hok = (unsigned)hh <= 9u;
      #pragma unroll
      for (int dw = 0; dw < 3; dw++){
        const int w3 = w2 + dw - 1;
        if (hok && ((unsigned)w3 <= 9u)){
          const f16* tp = t1L + (c + (dh-1)*10 + (dw-1))*20;
          const f16* wp = weffh + (dh*3+dw)*16;
          #pragma unroll
          for (int qq = 0; qq < 4; qq++){
            const f16x4 tv = *(const f16x4*)(tp + qq*4);
            const f16x4 wv = *(const f16x4*)(wp + qq*4);
            const f16x2 t01 = {tv[0], tv[1]}, t23 = {tv[2], tv[3]};
            const f16x2 w01 = {wv[0], wv[1]}, w23 = {wv[2], wv[3]};
            o = __builtin_amdgcn_fdot2(t01, w01, o, false);
            o = __builtin_amdgcn_fdot2(t23, w23, o, false);
          }
        }
      }
    }
    F[(size_t)pair*10000 + u*1000 + c] = (f16)o;
  }
}

// ---------------- k_attn_a: gnorm + softmax attention -> a_s, a_q ----------------
__global__ __launch_bounds__(256) void k_attn_a(const f16* __restrict__ F, float* __restrict__ av)
{
  __shared__ float fb[100*101 + 4];
  __shared__ float isc[100], ccs[100], isr[100], ccr[100];
  const int pair = blockIdx.x;
  const int t = threadIdx.x;
  const float L2T = 1.4426950408889634f * 0.2f;   // log2(e)/TEMP_ATTN

  for (int e = t; e < 10000; e += 256)
    fb[(e/100)*101 + (e%100)] = (float)F[(size_t)pair*10000 + e];
  __syncthreads();

  // waves 0-1: column stats (over uv, line=hw); waves 2-3: row stats (over hw, line=uv)
  {
    const int line = t & 127;
    const bool isCol = t < 128;
    if (line < 100){
      const int base = isCol ? line : line*101;
      const int stride = isCol ? 101 : 1;
      float s = 0.f, ss = 0.f;
      for (int i = 0; i < 100; i++){ const float x = fb[base + i*stride]; s += x; ss += x*x; }
      const float m = s * 0.01f;
      const float var = (ss - 100.f*m*m) * (1.f/99.f);
      const float is2 = rsqrtf(var + 1e-5f) * L2T;
      float S = 0.f;   // |zscore| <= sqrt(99): exp2 arg <= ~2.9, no max pass needed
      for (int i = 0; i < 100; i++) S += exp2f((fb[base + i*stride] - m) * is2);
      const float cc = m*is2 + log2f(S);
      if (isCol){ isc[line] = is2; ccs[line] = cc; }
      else      { isr[line] = is2; ccr[line] = cc; }
    }
  }
  __syncthreads();
  {
    const int line = t & 127;
    if (line < 100){
      if (t < 128){   // a_s[uv=line] = sum_hw softmax_col
        float a = 0.f;
        for (int k = 0; k < 100; k++)
          a += exp2f(fb[line*101 + k] * isc[k] - ccs[k]);
        av[(size_t)pair*200 + line] = a;
      } else {        // a_q[hw=line] = sum_uv softmax_row
        float a = 0.f;
        for (int k = 0; k < 100; k++)
          a += exp2f(fb[k*101 + line] * isr[k] - ccr[k]);
        av[(size_t)pair*200 + 100 + line] = a;
      }
    }
  }
}

// ---------------- k_attn_b: pooled prototypes + cosine; grid = 150 q-blocks ----------------
__global__ __launch_bounds__(256) void k_attn_b(
    const float* __restrict__ spt, const float* __restrict__ qry,
    const float* __restrict__ sptm, const float* __restrict__ qrym,
    const float* __restrict__ av, float* __restrict__ out)
{
  __shared__ __align__(16) float avs[1000];   // [w][200]
  __shared__ float Ms[5], Mq[5];
  __shared__ float red[4*15];
  const int q = blockIdx.x;
  const int t = threadIdx.x, wid = t >> 6;

  for (int e = t; e < 1000; e += 256)
    avs[e] = av[(size_t)(q*5 + e/200)*200 + (e%200)];
  __syncthreads();
  if (t < 10){
    const int w = t % 5; const bool isq = t >= 5;
    float s = 0.f;
    for (int ij = 0; ij < 100; ij++)
      s += avs[w*200 + (isq?100:0) + ij] * (isq ? qrym[q*100+ij] : sptm[w*100+ij]);
    if (isq) Mq[w] = s; else Ms[w] = s;
  }
  __syncthreads();

  float d0[5], d1[5], d2[5];
  #pragma unroll
  for (int w = 0; w < 5; w++){ d0[w]=0.f; d1[w]=0.f; d2[w]=0.f; }

  for (int c = t; c < 640; c += 256){
    float As[5], Aq[5];
    #pragma unroll
    for (int w = 0; w < 5; w++){ As[w]=0.f; Aq[w]=0.f; }
    const float4* qr = (const float4*)(qry + (size_t)q*64000 + (size_t)c*100);
    #pragma unroll 5
    for (int j4 = 0; j4 < 25; j4++){
      const float4 qv = qr[j4];
      #pragma unroll
      for (int w = 0; w < 5; w++){
        const float4 aq = ((const float4*)(avs + w*200 + 100))[j4];
        Aq[w] += aq.x*qv.x + aq.y*qv.y + aq.z*qv.z + aq.w*qv.w;
        const float4 as_ = ((const float4*)(avs + w*200))[j4];
        const float4 sv = ((const float4*)(spt + (size_t)w*64000 + (size_t)c*100))[j4];
        As[w] += as_.x*sv.x + as_.y*sv.y + as_.z*sv.z + as_.w*sv.w;
      }
    }
    #pragma unroll
    for (int w = 0; w < 5; w++){
      const float sp = As[w] - Ms[w], qp = Aq[w] - Mq[w];
      d0[w] += sp*qp; d1[w] += sp*sp; d2[w] += qp*qp;
    }
  }
  #pragma unroll
  for (int w = 0; w < 5; w++){
    #pragma unroll
    for (int msk = 1; msk < 64; msk <<= 1){
      d0[w] += __shfl_xor(d0[w], msk);
      d1[w] += __shfl_xor(d1[w], msk);
      d2[w] += __shfl_xor(d2[w], msk);
    }
  }
  if ((t & 63) == 0){
    #pragma unroll
    for (int w = 0; w < 5; w++){
      red[wid*15 + w*3+0] = d0[w];
      red[wid*15 + w*3+1] = d1[w];
      red[wid*15 + w*3+2] = d2[w];
    }
  }
  __syncthreads();
  if (t < 5){
    float e0=0.f, e1=0.f, e2=0.f;
    #pragma unroll
    for (int k = 0; k < 4; k++){
      e0 += red[k*15 + t*3+0];
      e1 += red[k*15 + t*3+1];
      e2 += red[k*15 + t*3+2];
    }
    const float den = fmaxf(sqrtf(e1), 1e-8f) * fmaxf(sqrtf(e2), 1e-8f);
    out[q*5 + t] = (e0 / den) * 5.0f;   // / TEMP(0.2)
  }
}

extern "C" void kernel_launch(void* const* d_in, const int* in_sizes, int n_in,
                              void* d_out, int out_size, void* d_ws, size_t ws_size,
                              hipStream_t stream)
{
  (void)in_sizes; (void)n_in; (void)out_size; (void)ws_size;
  const float* spt = (const float*)d_in[0];
  const float* qry = (const float*)d_in[1];
  const float* Wc  = (const float*)d_in[2];
  const float* gc  = (const float*)d_in[3];
  const float* bc  = (const float*)d_in[4];

  float* ws    = (float*)d_ws;
  float* cp    = ws;                         // 96 used (2560 reserved)
  float* sptm  = ws + 2560;                  // 500
  float* qrym  = ws + 3072;                  // 15000
  float* av    = ws + 18432;                 // 150000
  f16*  Apack  = (f16*)(ws + 168448);        // 2560 halves
  f16*  weffh  = (f16*)(ws + 169728);        // 144 halves
  f16*  s16    = (f16*)(ws + 169856);        // 5*7168
  f16*  q16    = (f16*)(ws + 187776);        // 150*7168
  f16*  z      = (f16*)(ws + 725376);        // 7.5M halves
  f16*  F      = (f16*)(ws + 4475376);       // 7.5M halves  (end ~32.9 MB)

  k_prep<<<1, 256, 0, stream>>>(
      (const float*)d_in[5],  (const float*)d_in[6],  (const float*)d_in[7],
      (const float*)d_in[8],  (const float*)d_in[9],  (const float*)d_in[10],
      (const float*)d_in[11], (const float*)d_in[12], (const float*)d_in[13],
      (const float*)d_in[14], (const float*)d_in[15], (const float*)d_in[16],
      (const float*)d_in[17], (const float*)d_in[18], (const float*)d_in[19],
      (const float*)d_in[20], (const float*)d_in[21], (const float*)d_in[22],
      cp, Apack, weffh);
  k_means<<<(500 + NQT*100 + 255)/256, 256, 0, stream>>>(spt, qry, sptm, qrym);
  k_feat<<<155, 256, 0, stream>>>(spt, qry, sptm, qrym, Wc, gc, bc, s16, q16);
  k_z<<<NQT*WAYT, 256, 0, stream>>>(s16, q16, cp, z);
  {
    dim3 grid(10, NQT*WAYT);
    k_l1<<<grid, 256, 0, stream>>>(z, cp, Apack, weffh, F);
  }
  k_attn_a<<<NQT*WAYT, 256, 0, stream>>>(F, av);
  k_attn_b<<<NQT, 256, 0, stream>>>(spt, qry, sptm, qrym, av, (float*)d_out);
}

// Round 5
// 337.557 us; speedup vs baseline: 5.7713x; 1.5765x over previous
//
#include <hip/hip_runtime.h>
#include <cstdint>
#include <cstddef>

#define NQT   150
#define WAYT  5
#define CCH   640

typedef _Float16 f16;
typedef _Float16 f16x2 __attribute__((ext_vector_type(2)));
typedef _Float16 f16x4 __attribute__((ext_vector_type(4)));
typedef _Float16 f16x8 __attribute__((ext_vector_type(8)));
typedef float    f32x4 __attribute__((ext_vector_type(4)));

static __device__ __forceinline__ f16x2 pkrtz(float a, float b){
  return __builtin_bit_cast(f16x2, __builtin_amdgcn_cvt_pkrtz(a, b));
}

// const-pack offsets (floats)
#define CP_A     0      // 16  gp*wp per cin
#define CP_B     16     // 16  bp per cin
#define CP_G2    32     // 16
#define CP_B2    48     // 16
#define CP_W20   64     // 9
#define CP_W10   73     // 9
#define CP_SC    82     // g2_0, b2_0, g1_0, b1_0, K

// ---------------- prep: cp, Apack (stage-1 A frags), Wf2 (stage-2 A frag) ----------------
__global__ __launch_bounds__(256) void k_prep(
    const float* __restrict__ s0_w2, const float* __restrict__ s0_g2, const float* __restrict__ s0_b2,
    const float* __restrict__ s0_w1, const float* __restrict__ s0_g1, const float* __restrict__ s0_b1,
    const float* __restrict__ s0_wp, const float* __restrict__ s0_gp, const float* __restrict__ s0_bp,
    const float* __restrict__ s1_w2, const float* __restrict__ s1_g2, const float* __restrict__ s1_b2,
    const float* __restrict__ s1_w1, const float* __restrict__ s1_g1, const float* __restrict__ s1_b1,
    const float* __restrict__ s1_wp, const float* __restrict__ s1_gp, const float* __restrict__ s1_bp,
    float* __restrict__ cp, f16* __restrict__ Apack, f16* __restrict__ Wf2)
{
  const int t = threadIdx.x;
  // Apack: [p(5)][lane(64)][j(8)] : A-frag for mfma_16x16x32_f16, taps paired along K
  for (int e = t; e < 2560; e += 256){
    int p = e / 512, r = e % 512, l = r / 8, j = r % 8;
    int kb = l >> 4;
    int tap = 2*p + (kb >> 1);       // 0..9
    int cin = (kb & 1)*8 + j;
    int co = l & 15;
    float v = 0.f;
    if (tap <= 8){
      int du = tap / 3, dv = tap % 3;
      v = s1_w2[((co*16 + cin)*3 + du)*3 + dv];
    }
    Apack[e] = (f16)v;
  }
  const float gp1 = s1_gp[0];
  // Wf2: [lane(64)][j(4)] A-frag for mfma_16x16x16_f16: A[row=tap][k=ci]
  {
    int l = t >> 2, j = t & 3;            // t < 256 exactly covers it
    int tap = l & 15, ci = ((l >> 4) << 2) + j;
    float v = 0.f;
    if (tap <= 8){
      for (int co = 0; co < 16; co++)
        v += gp1 * s1_wp[co] * s1_g1[co] * s1_w1[(co*16 + ci)*9 + tap];
    }
    Wf2[t] = (f16)v;
  }
  if (t < 16){
    cp[CP_A + t]  = s0_gp[t] * s0_wp[t];
    cp[CP_B + t]  = s0_bp[t];
    cp[CP_G2 + t] = s1_g2[t];
    cp[CP_B2 + t] = s1_b2[t];
  }
  if (t < 9){ cp[CP_W20 + t] = s0_w2[t]; cp[CP_W10 + t] = s0_w1[t]; }
  if (t == 0){
    cp[CP_SC + 0] = s0_g2[0]; cp[CP_SC + 1] = s0_b2[0];
    cp[CP_SC + 2] = s0_g1[0]; cp[CP_SC + 3] = s0_b1[0];
    float kk = 0.f;
    for (int co = 0; co < 16; co++) kk += s1_wp[co] * s1_b1[co];
    cp[CP_SC + 4] = gp1 * kk + s1_bp[0];
  }
}

// ---------------- prep2: W65 (f16, 80x640 with ones-row 64) + wsum ----------------
__global__ __launch_bounds__(256) void k_prep2(
    const float* __restrict__ W, f16* __restrict__ W65, float* __restrict__ wsum)
{
  const int b = blockIdx.x, t = threadIdx.x;
  if (b < 50){
    const int base = b*1024 + t*4;
    #pragma unroll
    for (int k = 0; k < 4; k++){
      const int idx = base + k;
      const int row = idx / 640, c = idx - row*640;
      float v = 0.f;
      if (row < 64) v = W[row*640 + c];
      else if (row == 64) v = 1.f;
      W65[idx] = (f16)v;
    }
  } else {
    const int o = t >> 2, qq = t & 3;
    float s = 0.f;
    for (int c = qq; c < 640; c += 4) s += W[o*640 + c];
    s += __shfl_xor(s, 1); s += __shfl_xor(s, 2);
    if (qq == 0) wsum[o] = s;
  }
}

// ---------------- feat: MFMA GEMM Y[80][112] = W65 x X, affine+relu+L2norm -> f16 [112][64] ----------------
__device__ __forceinline__ void feat_stage(const float* __restrict__ x, int kt, f16* __restrict__ dst, int t){
  for (int e = t; e < 800; e += 256){
    const int cc = e & 31, qd = e >> 5;   // lane-minor cc -> conflict-free LDS writes
    const float4 v4 = ((const float4*)(x + (size_t)(kt*32 + cc)*100))[qd];
    const int pb = qd*4;
    dst[(pb+0)*40 + cc] = (f16)v4.x;
    dst[(pb+1)*40 + cc] = (f16)v4.y;
    dst[(pb+2)*40 + cc] = (f16)v4.z;
    dst[(pb+3)*40 + cc] = (f16)v4.w;
  }
}

__global__ __launch_bounds__(256) void k_feat(
    const float* __restrict__ spt, const float* __restrict__ qry,
    const f16* __restrict__ W65, const float* __restrict__ wsum,
    const float* __restrict__ gg, const float* __restrict__ bb,
    f16* __restrict__ s16, f16* __restrict__ q16,
    float* __restrict__ sptm, float* __restrict__ qrym)
{
  __shared__ f16 Xs[2][112*40];           // rows 80B (odd multiple of 16B -> 2-way max)
  __shared__ float Ys[112*85];            // stride 85: gcd(21,32)=1 spread
  __shared__ float sg[64], sb[64], sw[64];
  const int n = blockIdx.x;
  const float* x; f16* out16; float* mout;
  if (n < 5){ x = spt + (size_t)n*64000; out16 = s16 + (size_t)n*7168; mout = sptm + n*100; }
  else { x = qry + (size_t)(n-5)*64000; out16 = q16 + (size_t)(n-5)*7168; mout = qrym + (size_t)(n-5)*100; }
  const int t = threadIdx.x, l = t & 63, wid = t >> 6;
  const int r16 = l & 15, kbq = (l >> 4) & 3;

  int mts[9], nts[9];
  #pragma unroll
  for (int s = 0; s < 9; s++){ const int mn = wid + s*4; mts[s] = mn/7; nts[s] = mn - (mn/7)*7; }
  f32x4 acc[9];
  #pragma unroll
  for (int s = 0; s < 9; s++) acc[s] = (f32x4){0.f,0.f,0.f,0.f};

  feat_stage(x, 0, Xs[0], t);
  __syncthreads();
  for (int kt = 0; kt < 20; kt++){
    if (kt < 19) feat_stage(x, kt+1, Xs[(kt+1)&1], t);
    const f16* xb = Xs[kt&1];
    #pragma unroll
    for (int s = 0; s < 9; s++){
      const int mn = wid + s*4;
      if (mn < 35){
        const f16x8 a8 = *(const f16x8*)(W65 + (size_t)(mts[s]*16 + r16)*640 + kt*32 + kbq*8);
        const f16x8 b8 = *(const f16x8*)(xb + (nts[s]*16 + r16)*40 + kbq*8);
        acc[s] = __builtin_amdgcn_mfma_f32_16x16x32_f16(a8, b8, acc[s], 0, 0, 0);
      }
    }
    __syncthreads();
  }
  #pragma unroll
  for (int s = 0; s < 9; s++){
    const int mn = wid + s*4;
    if (mn < 35){
      const int col = nts[s]*16 + r16, rb = mts[s]*16 + kbq*4;
      #pragma unroll
      for (int r = 0; r < 4; r++) Ys[col*85 + rb + r] = acc[s][r];
    }
  }
  if (t < 64){ sg[t] = gg[t]; sb[t] = bb[t]; sw[t] = wsum[t]; }
  __syncthreads();

  const int pix = t >> 1, half = t & 1;
  if (pix < 112){
    float yr[32]; float ssq = 0.f;
    const float m = Ys[pix*85 + 64] * (1.f/640.f);
    #pragma unroll
    for (int j = 0; j < 32; j++){
      const int o = half*32 + j;
      float yv = 0.f;
      if (pix < 100) yv = fmaxf(sg[o]*(Ys[pix*85 + o] - sw[o]*m) + sb[o], 0.f);
      yr[j] = yv; ssq += yv*yv;
    }
    ssq += __shfl_xor(ssq, 1);
    const float inv = (pix < 100) ? (1.f / fmaxf(sqrtf(ssq), 1e-8f)) : 0.f;
    #pragma unroll
    for (int j = 0; j < 16; j++){
      f16x2 hv = { (f16)(yr[2*j]*inv), (f16)(yr[2*j+1]*inv) };
      *(f16x2*)(out16 + pix*64 + half*32 + 2*j) = hv;
    }
    if (half == 0 && pix < 100) mout[pix] = m;
  }
}

// ---------------- k_z: MFMA corr + SepConv4d layer0 -> z (f16) ----------------
__global__ __launch_bounds__(256) void k_z(
    const f16* __restrict__ s16, const f16* __restrict__ q16,
    const float* __restrict__ cp, f16* __restrict__ z)
{
  __shared__ float cb[100*101 + 4];
  const int pair = blockIdx.x;
  const int q = pair / WAYT, w = pair % WAYT;
  const int t = threadIdx.x;
  const int l = t & 63, wid = t >> 6;
  const int r16 = l & 15, kb = (l >> 4) & 3;

  const f16* sbase = s16 + (size_t)w * 7168;
  const f16* qbase = q16 + (size_t)q * 7168;

  for (int mi = 0; mi < 2; mi++){
    const int mt = wid + mi*4;
    if (mt > 6) break;
    const f16x8 a0 = *(const f16x8*)(sbase + (mt*16 + r16)*64 + kb*8);
    const f16x8 a1 = *(const f16x8*)(sbase + (mt*16 + r16)*64 + 32 + kb*8);
    for (int nt = 0; nt < 7; nt++){
      const f16x8 b0 = *(const f16x8*)(qbase + (nt*16 + r16)*64 + kb*8);
      const f16x8 b1 = *(const f16x8*)(qbase + (nt*16 + r16)*64 + 32 + kb*8);
      f32x4 acc = {0.f,0.f,0.f,0.f};
      acc = __builtin_amdgcn_mfma_f32_16x16x32_f16(a0, b0, acc, 0, 0, 0);
      acc = __builtin_amdgcn_mfma_f32_16x16x32_f16(a1, b1, acc, 0, 0, 0);
      const int hw = nt*16 + r16;
      if (hw < 100){
        #pragma unroll
        for (int r = 0; r < 4; r++){
          const int uv = mt*16 + kb*4 + r;
          if (uv < 100) cb[uv*101 + hw] = acc[r];
        }
      }
    }
  }
  __syncthreads();

  const float g20 = cp[CP_SC+0], b20 = cp[CP_SC+1];
  float rr[50];
  const int lineB = t & 127, halfB = t >> 7;
  if (lineB < 100){
    const int hw = lineB;
    #pragma unroll
    for (int i = 0; i < 50; i++){
      const int u = halfB*5 + i/10, v = i % 10;
      float o = 0.f;
      #pragma unroll
      for (int du = 0; du < 3; du++){
        const int uu = u + du - 1;
        if (uu < 0 || uu > 9) continue;
        #pragma unroll
        for (int dv = 0; dv < 3; dv++){
          const int vv = v + dv - 1;
          if (vv < 0 || vv > 9) continue;
          o += cp[CP_W20 + du*3+dv] * cb[(uu*10+vv)*101 + hw];
        }
      }
      rr[i] = fmaxf(g20*o + b20, 0.f);
    }
  }
  __syncthreads();
  if (lineB < 100){
    #pragma unroll
    for (int i = 0; i < 50; i++)
      cb[(halfB*50 + i)*101 + lineB] = rr[i];
  }
  __syncthreads();

  const float g10 = cp[CP_SC+2], b10 = cp[CP_SC+3];
  if (lineB < 100){
    const int uv = lineB, hwhalf = halfB;
    #pragma unroll
    for (int k = 0; k < 50; k++){
      const int h = hwhalf*5 + k/10, ww = k % 10;
      float o = 0.f;
      #pragma unroll
      for (int dh = 0; dh < 3; dh++){
        const int hh = h + dh - 1;
        if (hh < 0 || hh > 9) continue;
        #pragma unroll
        for (int dw = 0; dw < 3; dw++){
          const int w2 = ww + dw - 1;
          if (w2 < 0 || w2 > 9) continue;
          o += cp[CP_W10 + dh*3+dw] * cb[uv*101 + hh*10 + w2];
        }
      }
      z[(size_t)pair*10000 + uv*100 + hwhalf*50 + k] = (f16)(g10*o + b10);
    }
  }
}

// ---------------- k_l1: layer1, pk-f16 B-build + double MFMA + G-gather; grid (10, 750) ----------------
__global__ __launch_bounds__(256, 4) void k_l1(
    const f16* __restrict__ z, const float* __restrict__ cp,
    const f16* __restrict__ Apack, const f16* __restrict__ Wf2, f16* __restrict__ F)
{
  __shared__ f16 z3[3*1216];        // z rows u-1..u+1, +100 col base; OOB slots masked at use
  __shared__ f16 Gs[1040*12];       // G[16+col][tap], 24B rows
  const int u = blockIdx.x, pair = blockIdx.y;
  const int t = threadIdx.x, l = t & 63, wid = t >> 6;
  const int r16 = l & 15, kb = (l >> 4) & 3;
  const int khi = kb & 1, half = kb >> 1;

  // stage z3 (f16x2 pairs)
  for (int e = t; e < 1500; e += 256){
    const int du = e / 500, c2 = e - du*500;
    const int ur = u + du - 1;
    f16x2 v = {(f16)0, (f16)0};
    if (ur >= 0 && ur <= 9) v = *(const f16x2*)(z + (size_t)pair*10000 + ur*1000 + c2*2);
    *(f16x2*)(z3 + du*1216 + 100 + c2*2) = v;
  }

  // per-lane constants
  f16x2 Ac2[4], Bc2[4];
  {
    const float4 a4a = ((const float4*)(cp + CP_A))[khi*2];
    const float4 a4b = ((const float4*)(cp + CP_A))[khi*2+1];
    const float4 b4a = ((const float4*)(cp + CP_B))[khi*2];
    const float4 b4b = ((const float4*)(cp + CP_B))[khi*2+1];
    Ac2[0] = (f16x2){(f16)a4a.x,(f16)a4a.y}; Ac2[1] = (f16x2){(f16)a4a.z,(f16)a4a.w};
    Ac2[2] = (f16x2){(f16)a4b.x,(f16)a4b.y}; Ac2[3] = (f16x2){(f16)a4b.z,(f16)a4b.w};
    Bc2[0] = (f16x2){(f16)b4a.x,(f16)b4a.y}; Bc2[1] = (f16x2){(f16)b4a.z,(f16)b4a.w};
    Bc2[2] = (f16x2){(f16)b4b.x,(f16)b4b.y}; Bc2[3] = (f16x2){(f16)b4b.z,(f16)b4b.w};
  }
  f16x8 af[5];
  #pragma unroll
  for (int p = 0; p < 5; p++) af[p] = ((const f16x8*)Apack)[p*64 + l];
  const f16x4 wf = ((const f16x4*)Wf2)[l];
  const float4 g4 = ((const float4*)(cp + CP_G2))[kb];
  const float4 b4 = ((const float4*)(cp + CP_B2))[kb];

  int zoffE[5], dvm[5];
  #pragma unroll
  for (int p = 0; p < 5; p++){
    const int tap = 2*p + half;
    const int du = (tap <= 8) ? tap/3 : 0;
    const int dv = (tap <= 8) ? tap%3 : 0;
    const bool ok0 = (tap <= 8) && (u + du - 1 >= 0) && (u + du - 1 <= 9);
    zoffE[p] = du*1216 + dv*100;
    dvm[p]  = ok0 ? (dv - 1) : 1000;
  }
  __syncthreads();

  const f16x2 zero2 = {(f16)0, (f16)0};
  // per 16-col tile: stage-1 MFMA (K=160 over taps*cin) -> t1 in regs -> stage-2 MFMA -> G
  #pragma unroll 1
  for (int i = 0; i < 16; i++){
    const int cbase = wid*256 + i*16;
    if (cbase >= 1008) break;            // wave-uniform
    const int c = cbase + r16;
    const int v = (c * 5243) >> 19;
    f32x4 acc = {0.f,0.f,0.f,0.f};
    #pragma unroll
    for (int p = 0; p < 5; p++){
      const f16 zv = z3[zoffE[p] + c];
      const f16x2 zz = {zv, zv};
      const bool okp = ((unsigned)(v + dvm[p])) <= 9u;
      union { f16x8 v8; f16x2 h2[4]; } bu;
      #pragma unroll
      for (int j2 = 0; j2 < 4; j2++){
        f16x2 r2 = Ac2[j2] * zz + Bc2[j2];               // v_pk_fma_f16
        r2 = __builtin_elementwise_max(r2, zero2);        // v_pk_max_f16
        bu.h2[j2] = okp ? r2 : zero2;                     // masked pad -> 0 (not relu(B))
      }
      acc = __builtin_amdgcn_mfma_f32_16x16x32_f16(af[p], bu.v8, acc, 0, 0, 0);
    }
    // epilogue: t1 = relu(g2*acc + b2) -> f16x4 (already in stage-2 B-frag layout!)
    const float r0 = fmaxf(g4.x*acc[0] + b4.x, 0.f);
    const float r1 = fmaxf(g4.y*acc[1] + b4.y, 0.f);
    const float r2f = fmaxf(g4.z*acc[2] + b4.z, 0.f);
    const float r3f = fmaxf(g4.w*acc[3] + b4.w, 0.f);
    union { f16x4 v4; f16x2 h2[2]; } t1u;
    t1u.h2[0] = pkrtz(r0, r1);
    t1u.h2[1] = pkrtz(r2f, r3f);
    // stage-2: G[tap][col] = sum_ci weff[tap][ci] * t1[ci][col]
    f32x4 g = {0.f,0.f,0.f,0.f};
    g = __builtin_amdgcn_mfma_f32_16x16x16f16(wf, t1u.v4, g, 0, 0, 0);
    if (kb < 3){
      union { f16x4 v4; f16x2 h2[2]; } gu;
      gu.h2[0] = pkrtz(g[0], g[1]);
      gu.h2[1] = pkrtz(g[2], g[3]);
      *(f16x4*)((char*)Gs + (size_t)(16 + c)*24 + kb*8) = gu.v4;
    }
  }
  __syncthreads();

  // gather: F[c] = K + sum_{valid taps} G[c + (dh-1)*10 + (dw-1)][dh*3+dw]
  const float Kc = cp[CP_SC+4];
  #pragma unroll 1
  for (int oo = 0; oo < 4; oo++){
    const int c = t + oo*256;
    if (c < 1000){
      const int hw = c - ((c * 5243) >> 19) * 100;
      const int h = (hw * 205) >> 11, w2 = hw - h*10;
      float o = Kc;
      #pragma unroll
      for (int dh = 0; dh < 3; dh++){
        #pragma unroll
        for (int dw = 0; dw < 3; dw++){
          const bool okg = ((unsigned)(h + dh - 1) <= 9u) && ((unsigned)(w2 + dw - 1) <= 9u);
          const int s = (dh - 1)*10 + (dw - 1);
          const float gv = (float)Gs[(size_t)(16 + c + s)*12 + dh*3 + dw];
          o += okg ? gv : 0.f;
        }
      }
      F[(size_t)pair*10000 + u*1000 + c] = (f16)o;
    }
  }
}

// ---------------- gnorm + softmax attention -> a_s, a_q ----------------
__global__ __launch_bounds__(256) void k_attn_a(const f16* __restrict__ F, float* __restrict__ av)
{
  __shared__ float fb[100*101 + 4];
  __shared__ float isc[100], ccs[100], isr[100], ccr[100];
  const int pair = blockIdx.x;
  const int t = threadIdx.x;
  const float L2T = 1.4426950408889634f * 0.2f;

  for (int e = t; e < 10000; e += 256)
    fb[(e/100)*101 + (e%100)] = (float)F[(size_t)pair*10000 + e];
  __syncthreads();

  {
    const int line = t & 127;
    const bool isCol = t < 128;
    if (line < 100){
      const int base = isCol ? line : line*101;
      const int stride = isCol ? 101 : 1;
      float s = 0.f, ss = 0.f;
      for (int i = 0; i < 100; i++){ const float x = fb[base + i*stride]; s += x; ss += x*x; }
      const float m = s * 0.01f;
      const float var = (ss - 100.f*m*m) * (1.f/99.f);
      const float is2 = rsqrtf(var + 1e-5f) * L2T;
      float S = 0.f;
      for (int i = 0; i < 100; i++) S += exp2f((fb[base + i*stride] - m) * is2);
      const float cc = m*is2 + log2f(S);
      if (isCol){ isc[line] = is2; ccs[line] = cc; }
      else      { isr[line] = is2; ccr[line] = cc; }
    }
  }
  __syncthreads();
  {
    const int line = t & 127;
    if (line < 100){
      if (t < 128){
        float a = 0.f;
        for (int k = 0; k < 100; k++)
          a += exp2f(fb[line*101 + k] * isc[k] - ccs[k]);
        av[(size_t)pair*200 + line] = a;
      } else {
        float a = 0.f;
        for (int k = 0; k < 100; k++)
          a += exp2f(fb[k*101 + line] * isr[k] - ccr[k]);
        av[(size_t)pair*200 + 100 + line] = a;
      }
    }
  }
}

// ---------------- pooled prototypes + cosine; grid = 150 q-blocks ----------------
__global__ __launch_bounds__(256) void k_attn_b(
    const float* __restrict__ spt, const float* __restrict__ qry,
    const float* __restrict__ sptm, const float* __restrict__ qrym,
    const float* __restrict__ av, float* __restrict__ out)
{
  __shared__ __align__(16) float avs[1000];
  __shared__ float Ms[5], Mq[5];
  __shared__ float red[4*15];
  const int q = blockIdx.x;
  const int t = threadIdx.x, wid = t >> 6;

  for (int e = t; e < 1000; e += 256)
    avs[e] = av[(size_t)(q*5 + e/200)*200 + (e%200)];
  __syncthreads();
  if (t < 10){
    const int w = t % 5; const bool isq = t >= 5;
    float s = 0.f;
    for (int ij = 0; ij < 100; ij++)
      s += avs[w*200 + (isq?100:0) + ij] * (isq ? qrym[q*100+ij] : sptm[w*100+ij]);
    if (isq) Mq[w] = s; else Ms[w] = s;
  }
  __syncthreads();

  float d0[5], d1[5], d2[5];
  #pragma unroll
  for (int w = 0; w < 5; w++){ d0[w]=0.f; d1[w]=0.f; d2[w]=0.f; }

  for (int c = t; c < 640; c += 256){
    float As[5], Aq[5];
    #pragma unroll
    for (int w = 0; w < 5; w++){ As[w]=0.f; Aq[w]=0.f; }
    const float4* qr = (const float4*)(qry + (size_t)q*64000 + (size_t)c*100);
    #pragma unroll 5
    for (int j4 = 0; j4 < 25; j4++){
      const float4 qv = qr[j4];
      #pragma unroll
      for (int w = 0; w < 5; w++){
        const float4 aq = ((const float4*)(avs + w*200 + 100))[j4];
        Aq[w] += aq.x*qv.x + aq.y*qv.y + aq.z*qv.z + aq.w*qv.w;
        const float4 as_ = ((const float4*)(avs + w*200))[j4];
        const float4 sv = ((const float4*)(spt + (size_t)w*64000 + (size_t)c*100))[j4];
        As[w] += as_.x*sv.x + as_.y*sv.y + as_.z*sv.z + as_.w*sv.w;
      }
    }
    #pragma unroll
    for (int w = 0; w < 5; w++){
      const float sp = As[w] - Ms[w], qp = Aq[w] - Mq[w];
      d0[w] += sp*qp; d1[w] += sp*sp; d2[w] += qp*qp;
    }
  }
  #pragma unroll
  for (int w = 0; w < 5; w++){
    #pragma unroll
    for (int msk = 1; msk < 64; msk <<= 1){
      d0[w] += __shfl_xor(d0[w], msk);
      d1[w] += __shfl_xor(d1[w], msk);
      d2[w] += __shfl_xor(d2[w], msk);
    }
  }
  if ((t & 63) == 0){
    #pragma unroll
    for (int w = 0; w < 5; w++){
      red[wid*15 + w*3+0] = d0[w];
      red[wid*15 + w*3+1] = d1[w];
      red[wid*15 + w*3+2] = d2[w];
    }
  }
  __syncthreads();
  if (t < 5){
    float e0=0.f, e1=0.f, e2=0.f;
    #pragma unroll
    for (int k = 0; k < 4; k++){
      e0 += red[k*15 + t*3+0];
      e1 += red[k*15 + t*3+1];
      e2 += red[k*15 + t*3+2];
    }
    const float den = fmaxf(sqrtf(e1), 1e-8f) * fmaxf(sqrtf(e2), 1e-8f);
    out[q*5 + t] = (e0 / den) * 5.0f;
  }
}

extern "C" void kernel_launch(void* const* d_in, const int* in_sizes, int n_in,
                              void* d_out, int out_size, void* d_ws, size_t ws_size,
                              hipStream_t stream)
{
  (void)in_sizes; (void)n_in; (void)out_size; (void)ws_size;
  const float* spt = (const float*)d_in[0];
  const float* qry = (const float*)d_in[1];
  const float* Wc  = (const float*)d_in[2];
  const float* gc  = (const float*)d_in[3];
  const float* bc  = (const float*)d_in[4];

  float* ws    = (float*)d_ws;
  float* cp    = ws;                          // 128
  float* wsum  = ws + 128;                    // 64
  float* sptm  = ws + 192;                    // 500
  float* qrym  = ws + 692;                    // 15000
  float* av    = ws + 15692;                  // 150000 -> 165692, pad to 165696
  f16*  Apack  = (f16*)(ws + 165696);         // 2560 f16
  f16*  Wf2    = (f16*)(ws + 166976);         // 256 f16
  f16*  W65    = (f16*)(ws + 167104);         // 51200 f16
  f16*  s16    = (f16*)(ws + 192704);         // 35840 f16
  f16*  q16    = (f16*)(ws + 210624);         // 1075200 f16
  f16*  z      = (f16*)(ws + 748224);         // 7.5M f16
  f16*  F      = (f16*)(ws + 4498224);        // 7.5M f16 (end ~33 MB)

  k_prep<<<1, 256, 0, stream>>>(
      (const float*)d_in[5],  (const float*)d_in[6],  (const float*)d_in[7],
      (const float*)d_in[8],  (const float*)d_in[9],  (const float*)d_in[10],
      (const float*)d_in[11], (const float*)d_in[12], (const float*)d_in[13],
      (const float*)d_in[14], (const float*)d_in[15], (const float*)d_in[16],
      (const float*)d_in[17], (const float*)d_in[18], (const float*)d_in[19],
      (const float*)d_in[20], (const float*)d_in[21], (const float*)d_in[22],
      cp, Apack, Wf2);
  k_prep2<<<51, 256, 0, stream>>>(Wc, W65, wsum);
  k_feat<<<155, 256, 0, stream>>>(spt, qry, W65, wsum, gc, bc, s16, q16, sptm, qrym);
  k_z<<<NQT*WAYT, 256, 0, stream>>>(s16, q16, cp, z);
  {
    dim3 grid(10, NQT*WAYT);
    k_l1<<<grid, 256, 0, stream>>>(z, cp, Apack, Wf2, F);
  }
  k_attn_a<<<NQT*WAYT, 256, 0, stream>>>(F, av);
  k_attn_b<<<NQT, 256, 0, stream>>>(spt, qry, sptm, qrym, av, (float*)d_out);
}

// Round 6
// 315.417 us; speedup vs baseline: 6.1764x; 1.0702x over previous
//
#include <hip/hip_runtime.h>
#include <cstdint>
#include <cstddef>

#define NQT   150
#define WAYT  5
#define CCH   640

typedef _Float16 f16;
typedef _Float16 f16x2 __attribute__((ext_vector_type(2)));
typedef _Float16 f16x4 __attribute__((ext_vector_type(4)));
typedef _Float16 f16x8 __attribute__((ext_vector_type(8)));
typedef float    f32x4 __attribute__((ext_vector_type(4)));

static __device__ __forceinline__ f16x2 pkrtz(float a, float b){
  return __builtin_bit_cast(f16x2, __builtin_amdgcn_cvt_pkrtz(a, b));
}

// const-pack offsets (floats)
#define CP_A     0      // 16  gp*wp per cin
#define CP_B     16     // 16  bp per cin
#define CP_G2    32     // 16
#define CP_B2    48     // 16
#define CP_W20   64     // 9
#define CP_W10   73     // 9
#define CP_SC    82     // g2_0, b2_0, g1_0, b1_0, K
#define CP_T9    96     // 144: T9[tap][co] = sum_cin (f16)W2[co,cin,tap]*relu((f16)bp[cin])

// stencil matrix value: Mat[k = src pos][n = dst pos], 10x10 grid, 3x3 taps
static __device__ __forceinline__ float stencil9(int k, int n, const float* __restrict__ w9){
  if (k >= 100 || n >= 100) return 0.f;
  const int a = n/10, b = n%10, a2 = k/10, b2 = k%10;
  const int dA = a2 - a + 1, dB = b2 - b + 1;
  if ((unsigned)dA > 2u || (unsigned)dB > 2u) return 0.f;
  return w9[dA*3 + dB];
}

// ---------------- prep (merged): cp/Apack/Wf2/T9, MuF, MhF, W65, wsum ----------------
__global__ __launch_bounds__(256) void k_prep_all(
    const float* __restrict__ W,
    const float* __restrict__ s0_w2, const float* __restrict__ s0_g2, const float* __restrict__ s0_b2,
    const float* __restrict__ s0_w1, const float* __restrict__ s0_g1, const float* __restrict__ s0_b1,
    const float* __restrict__ s0_wp, const float* __restrict__ s0_gp, const float* __restrict__ s0_bp,
    const float* __restrict__ s1_w2, const float* __restrict__ s1_g2, const float* __restrict__ s1_b2,
    const float* __restrict__ s1_w1, const float* __restrict__ s1_g1, const float* __restrict__ s1_b1,
    const float* __restrict__ s1_wp, const float* __restrict__ s1_gp, const float* __restrict__ s1_bp,
    float* __restrict__ cp, f16* __restrict__ Apack, f16* __restrict__ Wf2,
    f16* __restrict__ MuF, f16* __restrict__ MhF,
    f16* __restrict__ W65, float* __restrict__ wsum)
{
  const int b = blockIdx.x, t = threadIdx.x;
  if (b == 0){
    // Apack: [p(5)][lane(64)][j(8)] A-frag for mfma_16x16x32_f16, taps paired along K
    for (int e = t; e < 2560; e += 256){
      int p = e / 512, r = e % 512, l = r / 8, j = r % 8;
      int kb = l >> 4;
      int tap = 2*p + (kb >> 1);
      int cin = (kb & 1)*8 + j;
      int co = l & 15;
      float v = 0.f;
      if (tap <= 8){
        int du = tap / 3, dv = tap % 3;
        v = s1_w2[((co*16 + cin)*3 + du)*3 + dv];
      }
      Apack[e] = (f16)v;
    }
    const float gp1 = s1_gp[0];
    // Wf2: [lane(64)][j(4)] A-frag for mfma_16x16x16_f16: A[row=tap][k=ci]
    {
      int l = t >> 2, j = t & 3;
      int tap = l & 15, ci = ((l >> 4) << 2) + j;
      float v = 0.f;
      if (tap <= 8){
        for (int co = 0; co < 16; co++)
          v += gp1 * s1_wp[co] * s1_g1[co] * s1_w1[(co*16 + ci)*9 + tap];
      }
      Wf2[t] = (f16)v;
    }
    // T9[tap][co]
    if (t < 144){
      int tap = t / 16, co = t % 16;
      float s = 0.f;
      for (int cin = 0; cin < 16; cin++){
        float wv = (float)(f16)s1_w2[((co*16 + cin)*3 + tap/3)*3 + tap%3];
        float rb = fmaxf((float)(f16)s0_bp[cin], 0.f);
        s += wv * rb;
      }
      cp[CP_T9 + t] = s;
    }
    if (t < 16){
      cp[CP_A + t]  = s0_gp[t] * s0_wp[t];
      cp[CP_B + t]  = s0_bp[t];
      cp[CP_G2 + t] = s1_g2[t];
      cp[CP_B2 + t] = s1_b2[t];
    }
    if (t < 9){ cp[CP_W20 + t] = s0_w2[t]; cp[CP_W10 + t] = s0_w1[t]; }
    if (t == 0){
      cp[CP_SC + 0] = s0_g2[0]; cp[CP_SC + 1] = s0_b2[0];
      cp[CP_SC + 2] = s0_g1[0]; cp[CP_SC + 3] = s0_b1[0];
      float kk = 0.f;
      for (int co = 0; co < 16; co++) kk += s1_wp[co] * s1_b1[co];
      cp[CP_SC + 4] = gp1 * kk + s1_bp[0];
    }
  } else if (b <= 14){
    // MuF (b 1..7) / MhF (b 8..14): B-frag pack [nt(7)][kt(4)][l(64)][j(8)]
    const bool isMu = (b <= 7);
    f16* dst = isMu ? MuF : MhF;
    const float* w9 = isMu ? s0_w2 : s0_w1;   // both 9 contiguous floats
    const int base = (isMu ? (b-1) : (b-8)) * 2048;
    #pragma unroll
    for (int e2 = 0; e2 < 8; e2++){
      const int idx = base + e2*256 + t;
      const int j = idx & 7, l2 = (idx >> 3) & 63, ktnt = idx >> 9;
      const int kt = ktnt & 3, nt = ktnt >> 2;
      const int n = nt*16 + (l2 & 15);
      const int k = kt*32 + ((l2 >> 4) & 3)*8 + j;
      dst[idx] = (f16)stencil9(k, n, w9);
    }
  } else if (b <= 39){
    // W65: f16 80x640 with ones-row 64
    const int base = (b - 15) * 2048;
    #pragma unroll
    for (int e2 = 0; e2 < 8; e2++){
      const int idx = base + e2*256 + t;
      const int row = idx / 640, c = idx - row*640;
      float v = 0.f;
      if (row < 64) v = W[row*640 + c];
      else if (row == 64) v = 1.f;
      W65[idx] = (f16)v;
    }
  } else {
    const int o = t >> 2, qq = t & 3;
    float s = 0.f;
    for (int c = qq; c < 640; c += 4) s += W[o*640 + c];
    s += __shfl_xor(s, 1); s += __shfl_xor(s, 2);
    if (qq == 0) wsum[o] = s;
  }
}

// ---------------- feat: MFMA GEMM Y[80][112] = W65 x X, affine+relu+L2norm -> f16 [112][64] ----------------
__device__ __forceinline__ void feat_stage(const float* __restrict__ x, int kt, f16* __restrict__ dst, int t){
  for (int e = t; e < 800; e += 256){
    const int cc = e & 31, qd = e >> 5;
    const float4 v4 = ((const float4*)(x + (size_t)(kt*32 + cc)*100))[qd];
    const int pb = qd*4;
    dst[(pb+0)*40 + cc] = (f16)v4.x;
    dst[(pb+1)*40 + cc] = (f16)v4.y;
    dst[(pb+2)*40 + cc] = (f16)v4.z;
    dst[(pb+3)*40 + cc] = (f16)v4.w;
  }
}

__global__ __launch_bounds__(256) void k_feat(
    const float* __restrict__ spt, const float* __restrict__ qry,
    const f16* __restrict__ W65, const float* __restrict__ wsum,
    const float* __restrict__ gg, const float* __restrict__ bb,
    f16* __restrict__ s16, f16* __restrict__ q16,
    float* __restrict__ sptm, float* __restrict__ qrym)
{
  __shared__ f16 Xs[2][112*40];
  __shared__ float Ys[112*85];
  __shared__ float sg[64], sb[64], sw[64];
  const int n = blockIdx.x;
  const float* x; f16* out16; float* mout;
  if (n < 5){ x = spt + (size_t)n*64000; out16 = s16 + (size_t)n*7168; mout = sptm + n*100; }
  else { x = qry + (size_t)(n-5)*64000; out16 = q16 + (size_t)(n-5)*7168; mout = qrym + (size_t)(n-5)*100; }
  const int t = threadIdx.x, l = t & 63, wid = t >> 6;
  const int r16 = l & 15, kbq = (l >> 4) & 3;

  int mts[9], nts[9];
  #pragma unroll
  for (int s = 0; s < 9; s++){ const int mn = wid + s*4; mts[s] = mn/7; nts[s] = mn - (mn/7)*7; }
  f32x4 acc[9];
  #pragma unroll
  for (int s = 0; s < 9; s++) acc[s] = (f32x4){0.f,0.f,0.f,0.f};

  feat_stage(x, 0, Xs[0], t);
  __syncthreads();
  for (int kt = 0; kt < 20; kt++){
    if (kt < 19) feat_stage(x, kt+1, Xs[(kt+1)&1], t);
    const f16* xb = Xs[kt&1];
    #pragma unroll
    for (int s = 0; s < 9; s++){
      const int mn = wid + s*4;
      if (mn < 35){
        const f16x8 a8 = *(const f16x8*)(W65 + (size_t)(mts[s]*16 + r16)*640 + kt*32 + kbq*8);
        const f16x8 b8 = *(const f16x8*)(xb + (nts[s]*16 + r16)*40 + kbq*8);
        acc[s] = __builtin_amdgcn_mfma_f32_16x16x32_f16(a8, b8, acc[s], 0, 0, 0);
      }
    }
    __syncthreads();
  }
  #pragma unroll
  for (int s = 0; s < 9; s++){
    const int mn = wid + s*4;
    if (mn < 35){
      const int col = nts[s]*16 + r16, rb = mts[s]*16 + kbq*4;
      #pragma unroll
      for (int r = 0; r < 4; r++) Ys[col*85 + rb + r] = acc[s][r];
    }
  }
  if (t < 64){ sg[t] = gg[t]; sb[t] = bb[t]; sw[t] = wsum[t]; }
  __syncthreads();

  const int pix = t >> 1, half = t & 1;
  if (pix < 112){
    float yr[32]; float ssq = 0.f;
    const float m = Ys[pix*85 + 64] * (1.f/640.f);
    #pragma unroll
    for (int j = 0; j < 32; j++){
      const int o = half*32 + j;
      float yv = 0.f;
      if (pix < 100) yv = fmaxf(sg[o]*(Ys[pix*85 + o] - sw[o]*m) + sb[o], 0.f);
      yr[j] = yv; ssq += yv*yv;
    }
    ssq += __shfl_xor(ssq, 1);
    const float inv = (pix < 100) ? (1.f / fmaxf(sqrtf(ssq), 1e-8f)) : 0.f;
    #pragma unroll
    for (int j = 0; j < 16; j++){
      f16x2 hv = { (f16)(yr[2*j]*inv), (f16)(yr[2*j+1]*inv) };
      *(f16x2*)(out16 + pix*64 + half*32 + 2*j) = hv;
    }
    if (half == 0 && pix < 100) mout[pix] = m;
  }
}

// ---------------- k_z: corr + layer0 as three MFMA GEMMs -> z (f16) ----------------
// cbT[hw][uv'] (112x120 f16), tS[uv][hw'] (112x120 f16 + 16 zero tail)
__global__ __launch_bounds__(256, 3) void k_z(
    const f16* __restrict__ s16, const f16* __restrict__ q16,
    const float* __restrict__ cp, const f16* __restrict__ MuF, const f16* __restrict__ MhF,
    f16* __restrict__ z)
{
  __shared__ __align__(16) f16 smz[112*120 + 112*120 + 16];
  f16* cbT = smz;
  f16* tS  = smz + 112*120;
  const int pair = blockIdx.x;
  const int q = pair / WAYT, w = pair % WAYT;
  const int t = threadIdx.x, l = t & 63, wid = t >> 6;
  const int r16 = l & 15, kb = (l >> 4) & 3;

  // zero pad cols [112,120) of both buffers + tS head/tail (finite under overflow reads)
  {
    const f16x8 z8 = {(f16)0,(f16)0,(f16)0,(f16)0,(f16)0,(f16)0,(f16)0,(f16)0};
    if (t < 112){
      *(f16x8*)(cbT + t*120 + 112) = z8;
      *(f16x8*)(tS  + t*120 + 112) = z8;
    }
    if (t < 16) tS[112*120 + t] = (f16)0;
    if (t >= 240 && t < 248) tS[t - 240] = (f16)0;
  }

  const f16* sbase = s16 + (size_t)w * 7168;
  const f16* qbase = q16 + (size_t)q * 7168;

  // corr: C[uv][hw] = sum_c s[uv][c]*q[hw][c]; write transposed cbT[hw][uv]
  for (int mn = wid; mn < 49; mn += 4){
    const int mt = mn / 7, nt = mn - (mn/7)*7;
    const f16x8 a0 = *(const f16x8*)(sbase + (mt*16 + r16)*64 + kb*8);
    const f16x8 a1 = *(const f16x8*)(sbase + (mt*16 + r16)*64 + 32 + kb*8);
    const f16x8 b0 = *(const f16x8*)(qbase + (nt*16 + r16)*64 + kb*8);
    const f16x8 b1 = *(const f16x8*)(qbase + (nt*16 + r16)*64 + 32 + kb*8);
    f32x4 acc = {0.f,0.f,0.f,0.f};
    acc = __builtin_amdgcn_mfma_f32_16x16x32_f16(a0, b0, acc, 0, 0, 0);
    acc = __builtin_amdgcn_mfma_f32_16x16x32_f16(a1, b1, acc, 0, 0, 0);
    union { f16x4 v4; f16x2 h2[2]; } hv;
    hv.h2[0] = pkrtz(acc[0], acc[1]);
    hv.h2[1] = pkrtz(acc[2], acc[3]);
    *(f16x4*)(cbT + (nt*16 + r16)*120 + mt*16 + kb*4) = hv.v4;
  }
  __syncthreads();

  // GEMM1: out1[hw][uv] = cbT x Mu; t = relu(g20*out1+b20) -> tS[uv][hw]
  const float g20 = cp[CP_SC+0], b20 = cp[CP_SC+1];
  for (int mn = wid; mn < 49; mn += 4){
    const int mt = mn / 7, nt = mn - (mn/7)*7;   // mt: hw rows, nt: uv cols
    f32x4 acc = {0.f,0.f,0.f,0.f};
    #pragma unroll
    for (int kt = 0; kt < 4; kt++){
      const f16x8 a8 = *(const f16x8*)(cbT + (mt*16 + r16)*120 + kt*32 + kb*8);
      const f16x8 b8 = *(const f16x8*)(MuF + (size_t)(nt*4 + kt)*512 + l*8);
      acc = __builtin_amdgcn_mfma_f32_16x16x32_f16(a8, b8, acc, 0, 0, 0);
    }
    union { f16x4 v4; f16x2 h2[2]; } hv;
    hv.h2[0] = pkrtz(fmaxf(g20*acc[0] + b20, 0.f), fmaxf(g20*acc[1] + b20, 0.f));
    hv.h2[1] = pkrtz(fmaxf(g20*acc[2] + b20, 0.f), fmaxf(g20*acc[3] + b20, 0.f));
    *(f16x4*)(tS + (nt*16 + r16)*120 + mt*16 + kb*4) = hv.v4;
  }
  __syncthreads();

  // GEMM2: out2[uv][hw] = tS x Mh; z = g10*out2 + b10
  const float g10 = cp[CP_SC+2], b10 = cp[CP_SC+3];
  for (int mn = wid; mn < 49; mn += 4){
    const int mt = mn / 7, nt = mn - (mn/7)*7;   // mt: uv rows, nt: hw cols
    f32x4 acc = {0.f,0.f,0.f,0.f};
    #pragma unroll
    for (int kt = 0; kt < 4; kt++){
      const f16x8 a8 = *(const f16x8*)(tS + (mt*16 + r16)*120 + kt*32 + kb*8);
      const f16x8 b8 = *(const f16x8*)(MhF + (size_t)(nt*4 + kt)*512 + l*8);
      acc = __builtin_amdgcn_mfma_f32_16x16x32_f16(a8, b8, acc, 0, 0, 0);
    }
    const int hw = nt*16 + r16;
    if (hw < 100){
      #pragma unroll
      for (int r = 0; r < 4; r++){
        const int uv = mt*16 + kb*4 + r;
        if (uv < 100) z[(size_t)pair*10000 + uv*100 + hw] = (f16)(g10*acc[r] + b10);
      }
    }
  }
}

// ---------------- k_l1: layer1; zero-padded z3 + T9 bias-fold, Gs[tap][.] ----------------
__global__ __launch_bounds__(256, 6) void k_l1(
    const f16* __restrict__ z, const float* __restrict__ cp,
    const f16* __restrict__ Apack, const f16* __restrict__ Wf2, f16* __restrict__ F)
{
  __shared__ f16 z3[3*1216];        // rows u-1..u+1, cols: [0,100)=left pad, [100,1100)=data, [1100,1216)=right pad
  __shared__ f16 Gs[9*1072];        // G[tap][16 + col]
  const int u = blockIdx.x, pair = blockIdx.y;
  const int t = threadIdx.x, l = t & 63, wid = t >> 6;
  const int r16 = l & 15, kb = (l >> 4) & 3;
  const int khi = kb & 1, half = kb >> 1;

  // stage z3 full rows with zero pads (invalid du rows all-zero)
  for (int e = t; e < 1824; e += 256){
    const int du = e / 608, c2 = e - du*608;
    const int ur = u + du - 1;
    const int colb = c2*2;
    const int g = colb - 100;
    f16x2 v = {(f16)0, (f16)0};
    if (ur >= 0 && ur <= 9 && g >= 0 && g < 1000)
      v = *(const f16x2*)(z + (size_t)pair*10000 + ur*1000 + g);
    *(f16x2*)(z3 + du*1216 + colb) = v;
  }

  // per-lane constants
  f16x2 Ac2[4], Bc2[4];
  {
    const float4 a4a = ((const float4*)(cp + CP_A))[khi*2];
    const float4 a4b = ((const float4*)(cp + CP_A))[khi*2+1];
    const float4 b4a = ((const float4*)(cp + CP_B))[khi*2];
    const float4 b4b = ((const float4*)(cp + CP_B))[khi*2+1];
    Ac2[0] = (f16x2){(f16)a4a.x,(f16)a4a.y}; Ac2[1] = (f16x2){(f16)a4a.z,(f16)a4a.w};
    Ac2[2] = (f16x2){(f16)a4b.x,(f16)a4b.y}; Ac2[3] = (f16x2){(f16)a4b.z,(f16)a4b.w};
    Bc2[0] = (f16x2){(f16)b4a.x,(f16)b4a.y}; Bc2[1] = (f16x2){(f16)b4a.z,(f16)b4a.w};
    Bc2[2] = (f16x2){(f16)b4b.x,(f16)b4b.y}; Bc2[3] = (f16x2){(f16)b4b.z,(f16)b4b.w};
  }
  f16x8 af[5];
  #pragma unroll
  for (int p = 0; p < 5; p++) af[p] = ((const f16x8*)Apack)[p*64 + l];
  const f16x4 wf = ((const f16x4*)Wf2)[l];

  // fold pad-relu(B) corrections into 3 bias variants (mid / v==0 / v==9)
  float gv[4], bm[4], bv0[4], bv9[4];
  #pragma unroll
  for (int r = 0; r < 4; r++){
    const int co = kb*4 + r;
    gv[r] = cp[CP_G2 + co];
    const float b0 = cp[CP_B2 + co];
    float c0 = 0.f, cv0 = 0.f, cv9 = 0.f;
    #pragma unroll
    for (int du = 0; du < 3; du++){
      const int ur = u + du - 1;
      const float t0 = cp[CP_T9 + (du*3+0)*16 + co];
      const float t1 = cp[CP_T9 + (du*3+1)*16 + co];
      const float t2 = cp[CP_T9 + (du*3+2)*16 + co];
      if (ur < 0 || ur > 9) c0 += t0 + t1 + t2;
      else { cv0 += t0; cv9 += t2; }
    }
    bm[r]  = b0 - gv[r]*c0;
    bv0[r] = bm[r] - gv[r]*cv0;
    bv9[r] = bm[r] - gv[r]*cv9;
  }
  int zoffE[5];
  #pragma unroll
  for (int p = 0; p < 5; p++){
    const int tap = 2*p + half;
    const int du = (tap <= 8) ? tap/3 : 0;
    const int dv = (tap <= 8) ? tap%3 : 0;
    zoffE[p] = du*1216 + dv*100;
  }
  __syncthreads();

  const f16x2 zero2 = {(f16)0, (f16)0};
  #pragma unroll 1
  for (int i = 0; i < 16; i++){
    const int cbase = wid*256 + i*16;
    if (cbase >= 1008) break;            // wave-uniform
    const int c = cbase + r16;
    const int v = (c * 5243) >> 19;
    f32x4 acc = {0.f,0.f,0.f,0.f};
    #pragma unroll
    for (int p = 0; p < 5; p++){
      const f16 zv = z3[zoffE[p] + c];
      const f16x2 zz = {zv, zv};
      union { f16x8 v8; f16x2 h2[4]; } bu;
      #pragma unroll
      for (int j2 = 0; j2 < 4; j2++){
        f16x2 r2 = Ac2[j2] * zz + Bc2[j2];                 // v_pk_fma_f16
        bu.h2[j2] = __builtin_elementwise_max(r2, zero2);  // v_pk_max_f16 (pads -> relu(B), corrected via bias)
      }
      acc = __builtin_amdgcn_mfma_f32_16x16x32_f16(af[p], bu.v8, acc, 0, 0, 0);
    }
    const bool isv0 = (v == 0), isv9 = (v == 9);
    float rr[4];
    #pragma unroll
    for (int r = 0; r < 4; r++){
      const float bsel = isv0 ? bv0[r] : (isv9 ? bv9[r] : bm[r]);
      rr[r] = fmaxf(fmaf(gv[r], acc[r], bsel), 0.f);
    }
    union { f16x4 v4; f16x2 h2[2]; } t1u;
    t1u.h2[0] = pkrtz(rr[0], rr[1]);
    t1u.h2[1] = pkrtz(rr[2], rr[3]);
    f32x4 g = {0.f,0.f,0.f,0.f};
    g = __builtin_amdgcn_mfma_f32_16x16x16f16(wf, t1u.v4, g, 0, 0, 0);
    #pragma unroll
    for (int r = 0; r < 4; r++){
      const int tap = kb*4 + r;
      if (tap <= 8) Gs[tap*1072 + 16 + c] = (f16)g[r];
    }
  }
  __syncthreads();

  // gather: F[c] = K + sum_{valid taps} Gs[tap][16 + c + s]
  const float Kc = cp[CP_SC+4];
  #pragma unroll 1
  for (int oo = 0; oo < 4; oo++){
    const int c = t + oo*256;
    if (c < 1000){
      const int hw = c - ((c * 5243) >> 19) * 100;
      const int h = (hw * 205) >> 11, w2 = hw - h*10;
      float o = Kc;
      #pragma unroll
      for (int dh = 0; dh < 3; dh++){
        #pragma unroll
        for (int dw = 0; dw < 3; dw++){
          const bool okg = ((unsigned)(h + dh - 1) <= 9u) && ((unsigned)(w2 + dw - 1) <= 9u);
          const float gvv = (float)Gs[(dh*3+dw)*1072 + 16 + c + (dh-1)*10 + (dw-1)];
          o += okg ? gvv : 0.f;
        }
      }
      F[(size_t)pair*10000 + u*1000 + c] = (f16)o;
    }
  }
}

// ---------------- gnorm + softmax attention -> a_s, a_q ----------------
__global__ __launch_bounds__(256) void k_attn_a(const f16* __restrict__ F, float* __restrict__ av)
{
  __shared__ float fb[100*101 + 4];
  __shared__ float isc[100], ccs[100], isr[100], ccr[100];
  const int pair = blockIdx.x;
  const int t = threadIdx.x;
  const float L2T = 1.4426950408889634f * 0.2f;

  for (int e = t; e < 10000; e += 256)
    fb[(e/100)*101 + (e%100)] = (float)F[(size_t)pair*10000 + e];
  __syncthreads();

  {
    const int line = t & 127;
    const bool isCol = t < 128;
    if (line < 100){
      const int base = isCol ? line : line*101;
      const int stride = isCol ? 101 : 1;
      float s = 0.f, ss = 0.f;
      for (int i = 0; i < 100; i++){ const float x = fb[base + i*stride]; s += x; ss += x*x; }
      const float m = s * 0.01f;
      const float var = (ss - 100.f*m*m) * (1.f/99.f);
      const float is2 = rsqrtf(var + 1e-5f) * L2T;
      float S = 0.f;
      for (int i = 0; i < 100; i++) S += exp2f((fb[base + i*stride] - m) * is2);
      const float cc = m*is2 + log2f(S);
      if (isCol){ isc[line] = is2; ccs[line] = cc; }
      else      { isr[line] = is2; ccr[line] = cc; }
    }
  }
  __syncthreads();
  {
    const int line = t & 127;
    if (line < 100){
      if (t < 128){
        float a = 0.f;
        for (int k = 0; k < 100; k++)
          a += exp2f(fb[line*101 + k] * isc[k] - ccs[k]);
        av[(size_t)pair*200 + line] = a;
      } else {
        float a = 0.f;
        for (int k = 0; k < 100; k++)
          a += exp2f(fb[k*101 + line] * isr[k] - ccr[k]);
        av[(size_t)pair*200 + 100 + line] = a;
      }
    }
  }
}

// ---------------- pooled prototypes + cosine; grid = 150 q-blocks ----------------
__global__ __launch_bounds__(256) void k_attn_b(
    const float* __restrict__ spt, const float* __restrict__ qry,
    const float* __restrict__ sptm, const float* __restrict__ qrym,
    const float* __restrict__ av, float* __restrict__ out)
{
  __shared__ __align__(16) float avs[1000];
  __shared__ float Ms[5], Mq[5];
  __shared__ float red[4*15];
  const int q = blockIdx.x;
  const int t = threadIdx.x, wid = t >> 6;

  for (int e = t; e < 1000; e += 256)
    avs[e] = av[(size_t)(q*5 + e/200)*200 + (e%200)];
  __syncthreads();
  if (t < 10){
    const int w = t % 5; const bool isq = t >= 5;
    float s = 0.f;
    for (int ij = 0; ij < 100; ij++)
      s += avs[w*200 + (isq?100:0) + ij] * (isq ? qrym[q*100+ij] : sptm[w*100+ij]);
    if (isq) Mq[w] = s; else Ms[w] = s;
  }
  __syncthreads();

  float d0[5], d1[5], d2[5];
  #pragma unroll
  for (int w = 0; w < 5; w++){ d0[w]=0.f; d1[w]=0.f; d2[w]=0.f; }

  for (int c = t; c < 640; c += 256){
    float As[5], Aq[5];
    #pragma unroll
    for (int w = 0; w < 5; w++){ As[w]=0.f; Aq[w]=0.f; }
    const float4* qr = (const float4*)(qry + (size_t)q*64000 + (size_t)c*100);
    #pragma unroll 5
    for (int j4 = 0; j4 < 25; j4++){
      const float4 qv = qr[j4];
      #pragma unroll
      for (int w = 0; w < 5; w++){
        const float4 aq = ((const float4*)(avs + w*200 + 100))[j4];
        Aq[w] += aq.x*qv.x + aq.y*qv.y + aq.z*qv.z + aq.w*qv.w;
        const float4 as_ = ((const float4*)(avs + w*200))[j4];
        const float4 sv = ((const float4*)(spt + (size_t)w*64000 + (size_t)c*100))[j4];
        As[w] += as_.x*sv.x + as_.y*sv.y + as_.z*sv.z + as_.w*sv.w;
      }
    }
    #pragma unroll
    for (int w = 0; w < 5; w++){
      const float sp = As[w] - Ms[w], qp = Aq[w] - Mq[w];
      d0[w] += sp*qp; d1[w] += sp*sp; d2[w] += qp*qp;
    }
  }
  #pragma unroll
  for (int w = 0; w < 5; w++){
    #pragma unroll
    for (int msk = 1; msk < 64; msk <<= 1){
      d0[w] += __shfl_xor(d0[w], msk);
      d1[w] += __shfl_xor(d1[w], msk);
      d2[w] += __shfl_xor(d2[w], msk);
    }
  }
  if ((t & 63) == 0){
    #pragma unroll
    for (int w = 0; w < 5; w++){
      red[wid*15 + w*3+0] = d0[w];
      red[wid*15 + w*3+1] = d1[w];
      red[wid*15 + w*3+2] = d2[w];
    }
  }
  __syncthreads();
  if (t < 5){
    float e0=0.f, e1=0.f, e2=0.f;
    #pragma unroll
    for (int k = 0; k < 4; k++){
      e0 += red[k*15 + t*3+0];
      e1 += red[k*15 + t*3+1];
      e2 += red[k*15 + t*3+2];
    }
    const float den = fmaxf(sqrtf(e1), 1e-8f) * fmaxf(sqrtf(e2), 1e-8f);
    out[q*5 + t] = (e0 / den) * 5.0f;
  }
}

extern "C" void kernel_launch(void* const* d_in, const int* in_sizes, int n_in,
                              void* d_out, int out_size, void* d_ws, size_t ws_size,
                              hipStream_t stream)
{
  (void)in_sizes; (void)n_in; (void)out_size; (void)ws_size;
  const float* spt = (const float*)d_in[0];
  const float* qry = (const float*)d_in[1];
  const float* Wc  = (const float*)d_in[2];
  const float* gc  = (const float*)d_in[3];
  const float* bc  = (const float*)d_in[4];

  float* ws    = (float*)d_ws;
  float* cp    = ws;                          // 256
  float* wsum  = ws + 256;                    // 64
  float* sptm  = ws + 320;                    // 500
  float* qrym  = ws + 820;                    // 15000
  float* av    = ws + 15820;                  // 150000 -> 165820, pad to 165824
  f16*  Apack  = (f16*)(ws + 165824);         // 2560 f16
  f16*  Wf2    = (f16*)(ws + 167104);         // 256 f16
  f16*  W65    = (f16*)(ws + 167232);         // 51200 f16
  f16*  MuF    = (f16*)(ws + 192832);         // 14336 f16
  f16*  MhF    = (f16*)(ws + 200000);         // 14336 f16
  f16*  s16    = (f16*)(ws + 207168);         // 35840 f16
  f16*  q16    = (f16*)(ws + 225088);         // 1075200 f16
  f16*  z      = (f16*)(ws + 762688);         // 7.5M f16
  f16*  F      = (f16*)(ws + 4512688);        // 7.5M f16 (end ~33.1 MB)

  k_prep_all<<<41, 256, 0, stream>>>(
      Wc,
      (const float*)d_in[5],  (const float*)d_in[6],  (const float*)d_in[7],
      (const float*)d_in[8],  (const float*)d_in[9],  (const float*)d_in[10],
      (const float*)d_in[11], (const float*)d_in[12], (const float*)d_in[13],
      (const float*)d_in[14], (const float*)d_in[15], (const float*)d_in[16],
      (const float*)d_in[17], (const float*)d_in[18], (const float*)d_in[19],
      (const float*)d_in[20], (const float*)d_in[21], (const float*)d_in[22],
      cp, Apack, Wf2, MuF, MhF, W65, wsum);
  k_feat<<<155, 256, 0, stream>>>(spt, qry, W65, wsum, gc, bc, s16, q16, sptm, qrym);
  k_z<<<NQT*WAYT, 256, 0, stream>>>(s16, q16, cp, MuF, MhF, z);
  {
    dim3 grid(10, NQT*WAYT);
    k_l1<<<grid, 256, 0, stream>>>(z, cp, Apack, Wf2, F);
  }
  k_attn_a<<<NQT*WAYT, 256, 0, stream>>>(F, av);
  k_attn_b<<<NQT, 256, 0, stream>>>(spt, qry, sptm, qrym, av, (float*)d_out);
}

// Round 7
// 270.525 us; speedup vs baseline: 7.2014x; 1.1659x over previous
//
#include <hip/hip_runtime.h>
#include <cstdint>
#include <cstddef>

#define NQT   150
#define WAYT  5
#define CCH   640

typedef _Float16 f16;
typedef _Float16 f16x2 __attribute__((ext_vector_type(2)));
typedef _Float16 f16x4 __attribute__((ext_vector_type(4)));
typedef _Float16 f16x8 __attribute__((ext_vector_type(8)));
typedef float    f32x4 __attribute__((ext_vector_type(4)));

static __device__ __forceinline__ f16x2 pkrtz(float a, float b){
  return __builtin_bit_cast(f16x2, __builtin_amdgcn_cvt_pkrtz(a, b));
}

// const-pack offsets (floats)
#define CP_A     0
#define CP_B     16
#define CP_G2    32
#define CP_B2    48
#define CP_W20   64
#define CP_W10   73
#define CP_SC    82
#define CP_T9    96
#define GS_STRIDE 1076   // f16; 4-tap bank step = 8 -> conflict-free Gs writes

// stencil matrix value: Mat[k = src pos][n = dst pos], 10x10 grid, 3x3 taps
static __device__ __forceinline__ float stencil9(int k, int n, const float* __restrict__ w9){
  if (k >= 100 || n >= 100) return 0.f;
  const int a = n/10, b = n%10, a2 = k/10, b2 = k%10;
  const int dA = a2 - a + 1, dB = b2 - b + 1;
  if ((unsigned)dA > 2u || (unsigned)dB > 2u) return 0.f;
  return w9[dA*3 + dB];
}

// ---------------- prep (merged) ----------------
__global__ __launch_bounds__(256) void k_prep_all(
    const float* __restrict__ W,
    const float* __restrict__ s0_w2, const float* __restrict__ s0_g2, const float* __restrict__ s0_b2,
    const float* __restrict__ s0_w1, const float* __restrict__ s0_g1, const float* __restrict__ s0_b1,
    const float* __restrict__ s0_wp, const float* __restrict__ s0_gp, const float* __restrict__ s0_bp,
    const float* __restrict__ s1_w2, const float* __restrict__ s1_g2, const float* __restrict__ s1_b2,
    const float* __restrict__ s1_w1, const float* __restrict__ s1_g1, const float* __restrict__ s1_b1,
    const float* __restrict__ s1_wp, const float* __restrict__ s1_gp, const float* __restrict__ s1_bp,
    float* __restrict__ cp, f16* __restrict__ Apack, f16* __restrict__ Wf2,
    f16* __restrict__ MuF, f16* __restrict__ MhF,
    f16* __restrict__ W65, float* __restrict__ wsum)
{
  const int b = blockIdx.x, t = threadIdx.x;
  if (b == 0){
    for (int e = t; e < 2560; e += 256){
      int p = e / 512, r = e % 512, l = r / 8, j = r % 8;
      int kb = l >> 4;
      int tap = 2*p + (kb >> 1);
      int cin = (kb & 1)*8 + j;
      int co = l & 15;
      float v = 0.f;
      if (tap <= 8){
        int du = tap / 3, dv = tap % 3;
        v = s1_w2[((co*16 + cin)*3 + du)*3 + dv];
      }
      Apack[e] = (f16)v;
    }
    const float gp1 = s1_gp[0];
    {
      int l = t >> 2, j = t & 3;
      int tap = l & 15, ci = ((l >> 4) << 2) + j;
      float v = 0.f;
      if (tap <= 8){
        for (int co = 0; co < 16; co++)
          v += gp1 * s1_wp[co] * s1_g1[co] * s1_w1[(co*16 + ci)*9 + tap];
      }
      Wf2[t] = (f16)v;
    }
    if (t < 144){
      int tap = t / 16, co = t % 16;
      float s = 0.f;
      for (int cin = 0; cin < 16; cin++){
        float wv = (float)(f16)s1_w2[((co*16 + cin)*3 + tap/3)*3 + tap%3];
        float rb = fmaxf((float)(f16)s0_bp[cin], 0.f);
        s += wv * rb;
      }
      cp[CP_T9 + t] = s;
    }
    if (t < 16){
      cp[CP_A + t]  = s0_gp[t] * s0_wp[t];
      cp[CP_B + t]  = s0_bp[t];
      cp[CP_G2 + t] = s1_g2[t];
      cp[CP_B2 + t] = s1_b2[t];
    }
    if (t < 9){ cp[CP_W20 + t] = s0_w2[t]; cp[CP_W10 + t] = s0_w1[t]; }
    if (t == 0){
      cp[CP_SC + 0] = s0_g2[0]; cp[CP_SC + 1] = s0_b2[0];
      cp[CP_SC + 2] = s0_g1[0]; cp[CP_SC + 3] = s0_b1[0];
      float kk = 0.f;
      for (int co = 0; co < 16; co++) kk += s1_wp[co] * s1_b1[co];
      cp[CP_SC + 4] = gp1 * kk + s1_bp[0];
    }
  } else if (b <= 14){
    const bool isMu = (b <= 7);
    f16* dst = isMu ? MuF : MhF;
    const float* w9 = isMu ? s0_w2 : s0_w1;
    const int base = (isMu ? (b-1) : (b-8)) * 2048;
    #pragma unroll
    for (int e2 = 0; e2 < 8; e2++){
      const int idx = base + e2*256 + t;
      const int j = idx & 7, l2 = (idx >> 3) & 63, ktnt = idx >> 9;
      const int kt = ktnt & 3, nt = ktnt >> 2;
      const int n = nt*16 + (l2 & 15);
      const int k = kt*32 + ((l2 >> 4) & 3)*8 + j;
      dst[idx] = (f16)stencil9(k, n, w9);
    }
  } else if (b <= 39){
    const int base = (b - 15) * 2048;
    #pragma unroll
    for (int e2 = 0; e2 < 8; e2++){
      const int idx = base + e2*256 + t;
      const int row = idx / 640, c = idx - row*640;
      float v = 0.f;
      if (row < 64) v = W[row*640 + c];
      else if (row == 64) v = 1.f;
      W65[idx] = (f16)v;
    }
  } else {
    const int o = t >> 2, qq = t & 3;
    float s = 0.f;
    for (int c = qq; c < 640; c += 4) s += W[o*640 + c];
    s += __shfl_xor(s, 1); s += __shfl_xor(s, 2);
    if (qq == 0) wsum[o] = s;
  }
}

// ---------------- feat ----------------
__device__ __forceinline__ void feat_stage(const float* __restrict__ x, int kt, f16* __restrict__ dst, int t){
  for (int e = t; e < 800; e += 256){
    const int cc = e & 31, qd = e >> 5;
    const float4 v4 = ((const float4*)(x + (size_t)(kt*32 + cc)*100))[qd];
    const int pb = qd*4;
    dst[(pb+0)*40 + cc] = (f16)v4.x;
    dst[(pb+1)*40 + cc] = (f16)v4.y;
    dst[(pb+2)*40 + cc] = (f16)v4.z;
    dst[(pb+3)*40 + cc] = (f16)v4.w;
  }
}

__global__ __launch_bounds__(256) void k_feat(
    const float* __restrict__ spt, const float* __restrict__ qry,
    const f16* __restrict__ W65, const float* __restrict__ wsum,
    const float* __restrict__ gg, const float* __restrict__ bb,
    f16* __restrict__ s16, f16* __restrict__ q16,
    float* __restrict__ sptm, float* __restrict__ qrym)
{
  __shared__ f16 Xs[2][112*40];
  __shared__ float Ys[112*85];
  __shared__ float sg[64], sb[64], sw[64];
  const int n = blockIdx.x;
  const float* x; f16* out16; float* mout;
  if (n < 5){ x = spt + (size_t)n*64000; out16 = s16 + (size_t)n*7168; mout = sptm + n*100; }
  else { x = qry + (size_t)(n-5)*64000; out16 = q16 + (size_t)(n-5)*7168; mout = qrym + (size_t)(n-5)*100; }
  const int t = threadIdx.x, l = t & 63, wid = t >> 6;
  const int r16 = l & 15, kbq = (l >> 4) & 3;

  int mts[9], nts[9];
  #pragma unroll
  for (int s = 0; s < 9; s++){ const int mn = wid + s*4; mts[s] = mn/7; nts[s] = mn - (mn/7)*7; }
  f32x4 acc[9];
  #pragma unroll
  for (int s = 0; s < 9; s++) acc[s] = (f32x4){0.f,0.f,0.f,0.f};

  feat_stage(x, 0, Xs[0], t);
  __syncthreads();
  for (int kt = 0; kt < 20; kt++){
    if (kt < 19) feat_stage(x, kt+1, Xs[(kt+1)&1], t);
    const f16* xb = Xs[kt&1];
    #pragma unroll
    for (int s = 0; s < 9; s++){
      const int mn = wid + s*4;
      if (mn < 35){
        const f16x8 a8 = *(const f16x8*)(W65 + (size_t)(mts[s]*16 + r16)*640 + kt*32 + kbq*8);
        const f16x8 b8 = *(const f16x8*)(xb + (nts[s]*16 + r16)*40 + kbq*8);
        acc[s] = __builtin_amdgcn_mfma_f32_16x16x32_f16(a8, b8, acc[s], 0, 0, 0);
      }
    }
    __syncthreads();
  }
  #pragma unroll
  for (int s = 0; s < 9; s++){
    const int mn = wid + s*4;
    if (mn < 35){
      const int col = nts[s]*16 + r16, rb = mts[s]*16 + kbq*4;
      #pragma unroll
      for (int r = 0; r < 4; r++) Ys[col*85 + rb + r] = acc[s][r];
    }
  }
  if (t < 64){ sg[t] = gg[t]; sb[t] = bb[t]; sw[t] = wsum[t]; }
  __syncthreads();

  const int pix = t >> 1, half = t & 1;
  if (pix < 112){
    float yr[32]; float ssq = 0.f;
    const float m = Ys[pix*85 + 64] * (1.f/640.f);
    #pragma unroll
    for (int j = 0; j < 32; j++){
      const int o = half*32 + j;
      float yv = 0.f;
      if (pix < 100) yv = fmaxf(sg[o]*(Ys[pix*85 + o] - sw[o]*m) + sb[o], 0.f);
      yr[j] = yv; ssq += yv*yv;
    }
    ssq += __shfl_xor(ssq, 1);
    const float inv = (pix < 100) ? (1.f / fmaxf(sqrtf(ssq), 1e-8f)) : 0.f;
    #pragma unroll
    for (int j = 0; j < 16; j++){
      f16x2 hv = { (f16)(yr[2*j]*inv), (f16)(yr[2*j+1]*inv) };
      *(f16x2*)(out16 + pix*64 + half*32 + 2*j) = hv;
    }
    if (half == 0 && pix < 100) mout[pix] = m;
  }
}

// ---------------- k_z: corr + layer0 as three MFMA GEMMs -> z (f16) ----------------
__global__ __launch_bounds__(256, 3) void k_z(
    const f16* __restrict__ s16, const f16* __restrict__ q16,
    const float* __restrict__ cp, const f16* __restrict__ MuF, const f16* __restrict__ MhF,
    f16* __restrict__ z)
{
  __shared__ __align__(16) f16 smz[112*120 + 112*120 + 16];
  f16* cbT = smz;
  f16* tS  = smz + 112*120;
  const int pair = blockIdx.x;
  const int q = pair / WAYT, w = pair % WAYT;
  const int t = threadIdx.x, l = t & 63, wid = t >> 6;
  const int r16 = l & 15, kb = (l >> 4) & 3;

  {
    const f16x8 z8 = {(f16)0,(f16)0,(f16)0,(f16)0,(f16)0,(f16)0,(f16)0,(f16)0};
    if (t < 112){
      *(f16x8*)(cbT + t*120 + 112) = z8;
      *(f16x8*)(tS  + t*120 + 112) = z8;
    }
    if (t < 16) tS[112*120 + t] = (f16)0;
    if (t >= 240 && t < 248) tS[t - 240] = (f16)0;
  }

  const f16* sbase = s16 + (size_t)w * 7168;
  const f16* qbase = q16 + (size_t)q * 7168;

  for (int mn = wid; mn < 49; mn += 4){
    const int mt = mn / 7, nt = mn - (mn/7)*7;
    const f16x8 a0 = *(const f16x8*)(sbase + (mt*16 + r16)*64 + kb*8);
    const f16x8 a1 = *(const f16x8*)(sbase + (mt*16 + r16)*64 + 32 + kb*8);
    const f16x8 b0 = *(const f16x8*)(qbase + (nt*16 + r16)*64 + kb*8);
    const f16x8 b1 = *(const f16x8*)(qbase + (nt*16 + r16)*64 + 32 + kb*8);
    f32x4 acc = {0.f,0.f,0.f,0.f};
    acc = __builtin_amdgcn_mfma_f32_16x16x32_f16(a0, b0, acc, 0, 0, 0);
    acc = __builtin_amdgcn_mfma_f32_16x16x32_f16(a1, b1, acc, 0, 0, 0);
    union { f16x4 v4; f16x2 h2[2]; } hv;
    hv.h2[0] = pkrtz(acc[0], acc[1]);
    hv.h2[1] = pkrtz(acc[2], acc[3]);
    *(f16x4*)(cbT + (nt*16 + r16)*120 + mt*16 + kb*4) = hv.v4;
  }
  __syncthreads();

  const float g20 = cp[CP_SC+0], b20 = cp[CP_SC+1];
  for (int mn = wid; mn < 49; mn += 4){
    const int mt = mn / 7, nt = mn - (mn/7)*7;
    f32x4 acc = {0.f,0.f,0.f,0.f};
    #pragma unroll
    for (int kt = 0; kt < 4; kt++){
      const f16x8 a8 = *(const f16x8*)(cbT + (mt*16 + r16)*120 + kt*32 + kb*8);
      const f16x8 b8 = *(const f16x8*)(MuF + (size_t)(nt*4 + kt)*512 + l*8);
      acc = __builtin_amdgcn_mfma_f32_16x16x32_f16(a8, b8, acc, 0, 0, 0);
    }
    union { f16x4 v4; f16x2 h2[2]; } hv;
    hv.h2[0] = pkrtz(fmaxf(g20*acc[0] + b20, 0.f), fmaxf(g20*acc[1] + b20, 0.f));
    hv.h2[1] = pkrtz(fmaxf(g20*acc[2] + b20, 0.f), fmaxf(g20*acc[3] + b20, 0.f));
    *(f16x4*)(tS + (nt*16 + r16)*120 + mt*16 + kb*4) = hv.v4;
  }
  __syncthreads();

  const float g10 = cp[CP_SC+2], b10 = cp[CP_SC+3];
  for (int mn = wid; mn < 49; mn += 4){
    const int mt = mn / 7, nt = mn - (mn/7)*7;
    f32x4 acc = {0.f,0.f,0.f,0.f};
    #pragma unroll
    for (int kt = 0; kt < 4; kt++){
      const f16x8 a8 = *(const f16x8*)(tS + (mt*16 + r16)*120 + kt*32 + kb*8);
      const f16x8 b8 = *(const f16x8*)(MhF + (size_t)(nt*4 + kt)*512 + l*8);
      acc = __builtin_amdgcn_mfma_f32_16x16x32_f16(a8, b8, acc, 0, 0, 0);
    }
    const int hw = nt*16 + r16;
    if (hw < 100){
      #pragma unroll
      for (int r = 0; r < 4; r++){
        const int uv = mt*16 + kb*4 + r;
        if (uv < 100) z[(size_t)pair*10000 + uv*100 + hw] = (f16)(g10*acc[r] + b10);
      }
    }
  }
}

// ---------------- k_l1 ----------------
__global__ __launch_bounds__(256, 6) void k_l1(
    const f16* __restrict__ z, const float* __restrict__ cp,
    const f16* __restrict__ Apack, const f16* __restrict__ Wf2, f16* __restrict__ F)
{
  __shared__ f16 z3[3*1216];
  __shared__ f16 Gs[9*GS_STRIDE];
  const int u = blockIdx.x, pair = blockIdx.y;
  const int t = threadIdx.x, l = t & 63, wid = t >> 6;
  const int r16 = l & 15, kb = (l >> 4) & 3;
  const int khi = kb & 1, half = kb >> 1;

  for (int e = t; e < 1824; e += 256){
    const int du = e / 608, c2 = e - du*608;
    const int ur = u + du - 1;
    const int colb = c2*2;
    const int g = colb - 100;
    f16x2 v = {(f16)0, (f16)0};
    if (ur >= 0 && ur <= 9 && g >= 0 && g < 1000)
      v = *(const f16x2*)(z + (size_t)pair*10000 + ur*1000 + g);
    *(f16x2*)(z3 + du*1216 + colb) = v;
  }

  f16x2 Ac2[4], Bc2[4];
  {
    const float4 a4a = ((const float4*)(cp + CP_A))[khi*2];
    const float4 a4b = ((const float4*)(cp + CP_A))[khi*2+1];
    const float4 b4a = ((const float4*)(cp + CP_B))[khi*2];
    const float4 b4b = ((const float4*)(cp + CP_B))[khi*2+1];
    Ac2[0] = (f16x2){(f16)a4a.x,(f16)a4a.y}; Ac2[1] = (f16x2){(f16)a4a.z,(f16)a4a.w};
    Ac2[2] = (f16x2){(f16)a4b.x,(f16)a4b.y}; Ac2[3] = (f16x2){(f16)a4b.z,(f16)a4b.w};
    Bc2[0] = (f16x2){(f16)b4a.x,(f16)b4a.y}; Bc2[1] = (f16x2){(f16)b4a.z,(f16)b4a.w};
    Bc2[2] = (f16x2){(f16)b4b.x,(f16)b4b.y}; Bc2[3] = (f16x2){(f16)b4b.z,(f16)b4b.w};
  }
  f16x8 af[5];
  #pragma unroll
  for (int p = 0; p < 5; p++) af[p] = ((const f16x8*)Apack)[p*64 + l];
  const f16x4 wf = ((const f16x4*)Wf2)[l];

  float gv[4], bm[4], bv0[4], bv9[4];
  #pragma unroll
  for (int r = 0; r < 4; r++){
    const int co = kb*4 + r;
    gv[r] = cp[CP_G2 + co];
    const float b0 = cp[CP_B2 + co];
    float c0 = 0.f, cv0 = 0.f, cv9 = 0.f;
    #pragma unroll
    for (int du = 0; du < 3; du++){
      const int ur = u + du - 1;
      const float t0 = cp[CP_T9 + (du*3+0)*16 + co];
      const float t1 = cp[CP_T9 + (du*3+1)*16 + co];
      const float t2 = cp[CP_T9 + (du*3+2)*16 + co];
      if (ur < 0 || ur > 9) c0 += t0 + t1 + t2;
      else { cv0 += t0; cv9 += t2; }
    }
    bm[r]  = b0 - gv[r]*c0;
    bv0[r] = bm[r] - gv[r]*cv0;
    bv9[r] = bm[r] - gv[r]*cv9;
  }
  int zoffE[5];
  #pragma unroll
  for (int p = 0; p < 5; p++){
    const int tap = 2*p + half;
    const int du = (tap <= 8) ? tap/3 : 0;
    const int dv = (tap <= 8) ? tap%3 : 0;
    zoffE[p] = du*1216 + dv*100;
  }
  __syncthreads();

  const f16x2 zero2 = {(f16)0, (f16)0};
  #pragma unroll 1
  for (int i = 0; i < 16; i++){
    const int cbase = wid*256 + i*16;
    if (cbase >= 1008) break;
    const int c = cbase + r16;
    const int v = (c * 5243) >> 19;
    f32x4 acc = {0.f,0.f,0.f,0.f};
    #pragma unroll
    for (int p = 0; p < 5; p++){
      const f16 zv = z3[zoffE[p] + c];
      const f16x2 zz = {zv, zv};
      union { f16x8 v8; f16x2 h2[4]; } bu;
      #pragma unroll
      for (int j2 = 0; j2 < 4; j2++){
        f16x2 r2 = Ac2[j2] * zz + Bc2[j2];
        bu.h2[j2] = __builtin_elementwise_max(r2, zero2);
      }
      acc = __builtin_amdgcn_mfma_f32_16x16x32_f16(af[p], bu.v8, acc, 0, 0, 0);
    }
    const bool isv0 = (v == 0), isv9 = (v == 9);
    float rr[4];
    #pragma unroll
    for (int r = 0; r < 4; r++){
      const float bsel = isv0 ? bv0[r] : (isv9 ? bv9[r] : bm[r]);
      rr[r] = fmaxf(fmaf(gv[r], acc[r], bsel), 0.f);
    }
    union { f16x4 v4; f16x2 h2[2]; } t1u;
    t1u.h2[0] = pkrtz(rr[0], rr[1]);
    t1u.h2[1] = pkrtz(rr[2], rr[3]);
    f32x4 g = {0.f,0.f,0.f,0.f};
    g = __builtin_amdgcn_mfma_f32_16x16x16f16(wf, t1u.v4, g, 0, 0, 0);
    #pragma unroll
    for (int r = 0; r < 4; r++){
      const int tap = kb*4 + r;
      if (tap <= 8) Gs[tap*GS_STRIDE + 16 + c] = (f16)g[r];
    }
  }
  __syncthreads();

  const float Kc = cp[CP_SC+4];
  #pragma unroll 1
  for (int oo = 0; oo < 4; oo++){
    const int c = t + oo*256;
    if (c < 1000){
      const int hw = c - ((c * 5243) >> 19) * 100;
      const int h = (hw * 205) >> 11, w2 = hw - h*10;
      float o = Kc;
      #pragma unroll
      for (int dh = 0; dh < 3; dh++){
        #pragma unroll
        for (int dw = 0; dw < 3; dw++){
          const bool okg = ((unsigned)(h + dh - 1) <= 9u) && ((unsigned)(w2 + dw - 1) <= 9u);
          const float gvv = (float)Gs[(dh*3+dw)*GS_STRIDE + 16 + c + (dh-1)*10 + (dw-1)];
          o += okg ? gvv : 0.f;
        }
      }
      F[(size_t)pair*10000 + u*1000 + c] = (f16)o;
    }
  }
}

// ---------------- attn_a: gnorm + softmax -> asq[pair][256] (zero-padded rows) ----------------
__global__ __launch_bounds__(256) void k_attn_a(const f16* __restrict__ F, float* __restrict__ asq)
{
  __shared__ float fb[100*101 + 4];
  __shared__ float isc[100], ccs[100], isr[100], ccr[100];
  const int pair = blockIdx.x;
  const int t = threadIdx.x;
  const float L2T = 1.4426950408889634f * 0.2f;

  for (int e = t; e < 10000; e += 256)
    fb[(e/100)*101 + (e%100)] = (float)F[(size_t)pair*10000 + e];
  __syncthreads();

  {
    const int line = t & 127;
    const bool isCol = t < 128;
    if (line < 100){
      const int base = isCol ? line : line*101;
      const int stride = isCol ? 101 : 1;
      float s = 0.f, ss = 0.f;
      for (int i = 0; i < 100; i++){ const float x = fb[base + i*stride]; s += x; ss += x*x; }
      const float m = s * 0.01f;
      const float var = (ss - 100.f*m*m) * (1.f/99.f);
      const float is2 = rsqrtf(var + 1e-5f) * L2T;
      float S = 0.f;
      for (int i = 0; i < 100; i++) S += exp2f((fb[base + i*stride] - m) * is2);
      const float cc = m*is2 + log2f(S);
      if (isCol){ isc[line] = is2; ccs[line] = cc; }
      else      { isr[line] = is2; ccr[line] = cc; }
    }
  }
  __syncthreads();
  {
    const int line = t & 127;
    if (line < 100){
      if (t < 128){
        float a = 0.f;
        for (int k = 0; k < 100; k++)
          a += exp2f(fb[line*101 + k] * isc[k] - ccs[k]);
        asq[(size_t)pair*256 + line] = a;       // a_s
      } else {
        float a = 0.f;
        for (int k = 0; k < 100; k++)
          a += exp2f(fb[k*101 + line] * isr[k] - ccr[k]);
        asq[(size_t)pair*256 + 128 + line] = a; // a_q
      }
    } else {
      // zero pads for GEMM K=112..128 reads
      asq[(size_t)pair*256 + (t < 128 ? t : t)] = 0.f;
    }
  }
}

// ---------------- spqp: sp = a_s x spt^T (50 blocks), qp = a_q x qry^T (150 blocks) ----------------
__global__ __launch_bounds__(256) void k_spqp(
    const float* __restrict__ spt, const float* __restrict__ qry,
    const float* __restrict__ asq, float* __restrict__ P)
{
  const int b = blockIdx.x;
  const int t = threadIdx.x, l = t & 63, wid = t >> 6;
  const int r16 = l & 15, kb = (l >> 4) & 3;

  if (b < 50){
    const int w = b / 10, c0 = (b % 10) * 64;
    const int c = c0 + wid*16 + r16;
    f16x8 bf[4];
    #pragma unroll
    for (int kt = 0; kt < 4; kt++){
      const int kbase = kt*32 + kb*8;
      float v[8];
      #pragma unroll
      for (int j = 0; j < 8; j++){
        const int k = kbase + j;
        v[j] = (k < 100) ? spt[(size_t)w*64000 + (size_t)c*100 + k] : 0.f;
      }
      union { f16x8 v8; f16x2 h2[4]; } u;
      #pragma unroll
      for (int j2 = 0; j2 < 4; j2++) u.h2[j2] = pkrtz(v[2*j2], v[2*j2+1]);
      bf[kt] = u.v8;
    }
    #pragma unroll 1
    for (int mt = 0; mt < 10; mt++){
      const int qr = mt*16 + r16;
      f32x4 acc = {0.f,0.f,0.f,0.f};
      #pragma unroll
      for (int kt = 0; kt < 4; kt++){
        const int kbase = kt*32 + kb*8;
        float v[8];
        #pragma unroll
        for (int j = 0; j < 8; j++)
          v[j] = (qr < 150) ? asq[(size_t)(qr*5 + w)*256 + kbase + j] : 0.f;
        union { f16x8 v8; f16x2 h2[4]; } u;
        #pragma unroll
        for (int j2 = 0; j2 < 4; j2++) u.h2[j2] = pkrtz(v[2*j2], v[2*j2+1]);
        acc = __builtin_amdgcn_mfma_f32_16x16x32_f16(u.v8, bf[kt], acc, 0, 0, 0);
      }
      #pragma unroll
      for (int r = 0; r < 4; r++){
        const int q2 = mt*16 + kb*4 + r;
        if (q2 < 150) P[(size_t)(q2*5 + w)*1280 + c0 + wid*16 + (l & 15)] = acc[r];
      }
    }
  } else {
    const int q = b - 50;
    f16x8 af[4];
    #pragma unroll
    for (int kt = 0; kt < 4; kt++){
      const int kbase = kt*32 + kb*8;
      float v[8];
      #pragma unroll
      for (int j = 0; j < 8; j++)
        v[j] = (r16 < 5) ? asq[(size_t)(q*5 + r16)*256 + 128 + kbase + j] : 0.f;
      union { f16x8 v8; f16x2 h2[4]; } u;
      #pragma unroll
      for (int j2 = 0; j2 < 4; j2++) u.h2[j2] = pkrtz(v[2*j2], v[2*j2+1]);
      af[kt] = u.v8;
    }
    #pragma unroll 1
    for (int nt = wid; nt < 40; nt += 4){
      const int c = nt*16 + r16;
      f32x4 acc = {0.f,0.f,0.f,0.f};
      #pragma unroll
      for (int kt = 0; kt < 4; kt++){
        const int kbase = kt*32 + kb*8;
        float v[8];
        #pragma unroll
        for (int j = 0; j < 8; j++){
          const int k = kbase + j;
          v[j] = (k < 100) ? qry[(size_t)q*64000 + (size_t)c*100 + k] : 0.f;
        }
        union { f16x8 v8; f16x2 h2[4]; } u;
        #pragma unroll
        for (int j2 = 0; j2 < 4; j2++) u.h2[j2] = pkrtz(v[2*j2], v[2*j2+1]);
        acc = __builtin_amdgcn_mfma_f32_16x16x32_f16(af[kt], u.v8, acc, 0, 0, 0);
      }
      #pragma unroll
      for (int r = 0; r < 4; r++){
        const int w2 = kb*4 + r;
        if (w2 < 5) P[(size_t)(q*5 + w2)*1280 + 640 + nt*16 + (l & 15)] = acc[r];
      }
    }
  }
}

// ---------------- cos: mean-correct + cosine per pair ----------------
__global__ __launch_bounds__(256) void k_cos(
    const float* __restrict__ P, const float* __restrict__ asq,
    const float* __restrict__ sptm, const float* __restrict__ qrym,
    float* __restrict__ out)
{
  __shared__ float pred[4];
  __shared__ float MsMq[2];
  __shared__ float red[12];
  const int pair = blockIdx.x;
  const int q = pair / WAYT, w = pair % WAYT;
  const int t = threadIdx.x, wid = t >> 6;

  float pm = 0.f;
  if (t < 100) pm = asq[(size_t)pair*256 + t] * sptm[w*100 + t];
  else if (t >= 128 && t < 228) pm = asq[(size_t)pair*256 + t] * qrym[q*100 + (t - 128)];
  #pragma unroll
  for (int m = 1; m < 64; m <<= 1) pm += __shfl_xor(pm, m);
  if ((t & 63) == 0) pred[wid] = pm;
  __syncthreads();
  if (t == 0) MsMq[0] = pred[0] + pred[1];
  if (t == 1) MsMq[1] = pred[2] + pred[3];
  __syncthreads();
  const float Ms = MsMq[0], Mq = MsMq[1];

  float d0 = 0.f, d1 = 0.f, d2 = 0.f;
  for (int c = t; c < 640; c += 256){
    const float sp = P[(size_t)pair*1280 + c] - Ms;
    const float qp = P[(size_t)pair*1280 + 640 + c] - Mq;
    d0 += sp*qp; d1 += sp*sp; d2 += qp*qp;
  }
  #pragma unroll
  for (int m = 1; m < 64; m <<= 1){
    d0 += __shfl_xor(d0, m); d1 += __shfl_xor(d1, m); d2 += __shfl_xor(d2, m);
  }
  if ((t & 63) == 0){ red[wid*3+0] = d0; red[wid*3+1] = d1; red[wid*3+2] = d2; }
  __syncthreads();
  if (t == 0){
    float e0 = 0.f, e1 = 0.f, e2 = 0.f;
    #pragma unroll
    for (int k = 0; k < 4; k++){ e0 += red[k*3]; e1 += red[k*3+1]; e2 += red[k*3+2]; }
    const float den = fmaxf(sqrtf(e1), 1e-8f) * fmaxf(sqrtf(e2), 1e-8f);
    out[pair] = (e0 / den) * 5.0f;
  }
}

extern "C" void kernel_launch(void* const* d_in, const int* in_sizes, int n_in,
                              void* d_out, int out_size, void* d_ws, size_t ws_size,
                              hipStream_t stream)
{
  (void)in_sizes; (void)n_in; (void)out_size; (void)ws_size;
  const float* spt = (const float*)d_in[0];
  const float* qry = (const float*)d_in[1];
  const float* Wc  = (const float*)d_in[2];
  const float* gc  = (const float*)d_in[3];
  const float* bc  = (const float*)d_in[4];

  float* ws    = (float*)d_ws;
  float* cp    = ws;                          // 256
  float* wsum  = ws + 256;                    // 64
  float* sptm  = ws + 320;                    // 500
  float* qrym  = ws + 820;                    // 15000 -> 15820, pad 15872
  f16*  Apack  = (f16*)(ws + 15872);          // 2560 f16 -> +1280
  f16*  Wf2    = (f16*)(ws + 17152);          // 256 f16  -> +128
  f16*  W65    = (f16*)(ws + 17280);          // 51200 f16 -> +25600
  f16*  MuF    = (f16*)(ws + 42880);          // 14336 f16 -> +7168
  f16*  MhF    = (f16*)(ws + 50048);          // 14336 f16 -> +7168
  f16*  s16    = (f16*)(ws + 57216);          // 35840 f16 -> +17920
  f16*  q16    = (f16*)(ws + 75136);          // 1075200 f16 -> +537600
  f16*  z      = (f16*)(ws + 612736);         // 7.5M f16 -> +3750000
  f16*  F      = (f16*)(ws + 4362736);        // 7.5M f16 (end 32.45 MB)
  // aliases (lifetime-disjoint):
  float* asq   = ws + 75136;                  // over q16 (dead after k_z); 192000 f32
  float* P     = ws + 612736;                 // over z   (dead after k_l1); 960000 f32

  k_prep_all<<<41, 256, 0, stream>>>(
      Wc,
      (const float*)d_in[5],  (const float*)d_in[6],  (const float*)d_in[7],
      (const float*)d_in[8],  (const float*)d_in[9],  (const float*)d_in[10],
      (const float*)d_in[11], (const float*)d_in[12], (const float*)d_in[13],
      (const float*)d_in[14], (const float*)d_in[15], (const float*)d_in[16],
      (const float*)d_in[17], (const float*)d_in[18], (const float*)d_in[19],
      (const float*)d_in[20], (const float*)d_in[21], (const float*)d_in[22],
      cp, Apack, Wf2, MuF, MhF, W65, wsum);
  k_feat<<<155, 256, 0, stream>>>(spt, qry, W65, wsum, gc, bc, s16, q16, sptm, qrym);
  k_z<<<NQT*WAYT, 256, 0, stream>>>(s16, q16, cp, MuF, MhF, z);
  {
    dim3 grid(10, NQT*WAYT);
    k_l1<<<grid, 256, 0, stream>>>(z, cp, Apack, Wf2, F);
  }
  k_attn_a<<<NQT*WAYT, 256, 0, stream>>>(F, asq);
  k_spqp<<<200, 256, 0, stream>>>(spt, qry, asq, P);
  k_cos<<<NQT*WAYT, 256, 0, stream>>>(P, asq, sptm, qrym, (float*)d_out);
}

// Round 8
// 252.470 us; speedup vs baseline: 7.7164x; 1.0715x over previous
//
#include <hip/hip_runtime.h>
#include <cstdint>
#include <cstddef>

#define NQT   150
#define WAYT  5
#define CCH   640

typedef _Float16 f16;
typedef _Float16 f16x2 __attribute__((ext_vector_type(2)));
typedef _Float16 f16x4 __attribute__((ext_vector_type(4)));
typedef _Float16 f16x8 __attribute__((ext_vector_type(8)));
typedef float    f32x4 __attribute__((ext_vector_type(4)));

static __device__ __forceinline__ f16x2 pkrtz(float a, float b){
  return __builtin_bit_cast(f16x2, __builtin_amdgcn_cvt_pkrtz(a, b));
}

// const-pack offsets (floats)
#define CP_A     0
#define CP_B     16
#define CP_G2    32
#define CP_B2    48
#define CP_W20   64
#define CP_W10   73
#define CP_SC    82
#define CP_T9    96
#define GS_STRIDE 1076   // f16; 4-tap bank step = 8 -> conflict-free Gs writes

// stencil matrix value: Mat[k = src pos][n = dst pos], 10x10 grid, 3x3 taps
static __device__ __forceinline__ float stencil9(int k, int n, const float* __restrict__ w9){
  if (k >= 100 || n >= 100) return 0.f;
  const int a = n/10, b = n%10, a2 = k/10, b2 = k%10;
  const int dA = a2 - a + 1, dB = b2 - b + 1;
  if ((unsigned)dA > 2u || (unsigned)dB > 2u) return 0.f;
  return w9[dA*3 + dB];
}

// ---------------- prep (merged) ----------------
__global__ __launch_bounds__(256) void k_prep_all(
    const float* __restrict__ W,
    const float* __restrict__ s0_w2, const float* __restrict__ s0_g2, const float* __restrict__ s0_b2,
    const float* __restrict__ s0_w1, const float* __restrict__ s0_g1, const float* __restrict__ s0_b1,
    const float* __restrict__ s0_wp, const float* __restrict__ s0_gp, const float* __restrict__ s0_bp,
    const float* __restrict__ s1_w2, const float* __restrict__ s1_g2, const float* __restrict__ s1_b2,
    const float* __restrict__ s1_w1, const float* __restrict__ s1_g1, const float* __restrict__ s1_b1,
    const float* __restrict__ s1_wp, const float* __restrict__ s1_gp, const float* __restrict__ s1_bp,
    float* __restrict__ cp, f16* __restrict__ Apack, f16* __restrict__ Wf2,
    f16* __restrict__ MuF, f16* __restrict__ MhF,
    f16* __restrict__ W65, float* __restrict__ wsum)
{
  const int b = blockIdx.x, t = threadIdx.x;
  if (b == 0){
    for (int e = t; e < 2560; e += 256){
      int p = e / 512, r = e % 512, l = r / 8, j = r % 8;
      int kb = l >> 4;
      int tap = 2*p + (kb >> 1);
      int cin = (kb & 1)*8 + j;
      int co = l & 15;
      float v = 0.f;
      if (tap <= 8){
        int du = tap / 3, dv = tap % 3;
        v = s1_w2[((co*16 + cin)*3 + du)*3 + dv];
      }
      Apack[e] = (f16)v;
    }
    const float gp1 = s1_gp[0];
    {
      int l = t >> 2, j = t & 3;
      int tap = l & 15, ci = ((l >> 4) << 2) + j;
      float v = 0.f;
      if (tap <= 8){
        for (int co = 0; co < 16; co++)
          v += gp1 * s1_wp[co] * s1_g1[co] * s1_w1[(co*16 + ci)*9 + tap];
      }
      Wf2[t] = (f16)v;
    }
    if (t < 144){
      int tap = t / 16, co = t % 16;
      float s = 0.f;
      for (int cin = 0; cin < 16; cin++){
        float wv = (float)(f16)s1_w2[((co*16 + cin)*3 + tap/3)*3 + tap%3];
        float rb = fmaxf((float)(f16)s0_bp[cin], 0.f);
        s += wv * rb;
      }
      cp[CP_T9 + t] = s;
    }
    if (t < 16){
      cp[CP_A + t]  = s0_gp[t] * s0_wp[t];
      cp[CP_B + t]  = s0_bp[t];
      cp[CP_G2 + t] = s1_g2[t];
      cp[CP_B2 + t] = s1_b2[t];
    }
    if (t < 9){ cp[CP_W20 + t] = s0_w2[t]; cp[CP_W10 + t] = s0_w1[t]; }
    if (t == 0){
      cp[CP_SC + 0] = s0_g2[0]; cp[CP_SC + 1] = s0_b2[0];
      cp[CP_SC + 2] = s0_g1[0]; cp[CP_SC + 3] = s0_b1[0];
      float kk = 0.f;
      for (int co = 0; co < 16; co++) kk += s1_wp[co] * s1_b1[co];
      cp[CP_SC + 4] = gp1 * kk + s1_bp[0];
    }
  } else if (b <= 14){
    const bool isMu = (b <= 7);
    f16* dst = isMu ? MuF : MhF;
    const float* w9 = isMu ? s0_w2 : s0_w1;
    const int base = (isMu ? (b-1) : (b-8)) * 2048;
    #pragma unroll
    for (int e2 = 0; e2 < 8; e2++){
      const int idx = base + e2*256 + t;
      const int j = idx & 7, l2 = (idx >> 3) & 63, ktnt = idx >> 9;
      const int kt = ktnt & 3, nt = ktnt >> 2;
      const int n = nt*16 + (l2 & 15);
      const int k = kt*32 + ((l2 >> 4) & 3)*8 + j;
      dst[idx] = (f16)stencil9(k, n, w9);
    }
  } else if (b <= 39){
    const int base = (b - 15) * 2048;
    #pragma unroll
    for (int e2 = 0; e2 < 8; e2++){
      const int idx = base + e2*256 + t;
      const int row = idx / 640, c = idx - row*640;
      float v = 0.f;
      if (row < 64) v = W[row*640 + c];
      else if (row == 64) v = 1.f;
      W65[idx] = (f16)v;
    }
  } else {
    const int o = t >> 2, qq = t & 3;
    float s = 0.f;
    for (int c = qq; c < 640; c += 4) s += W[o*640 + c];
    s += __shfl_xor(s, 1); s += __shfl_xor(s, 2);
    if (qq == 0) wsum[o] = s;
  }
}

// ---------------- feat: 620 blocks (image n x pixel-quarter); GEMM Y[80][32] per block ----------------
__device__ __forceinline__ void feat_stage4(const float* __restrict__ x, int pixoff, int kt,
                                            f16* __restrict__ dst, int t){
  if (t < 224){
    const int cc = t / 7, qd = t % 7;      // cc: K-row 0..31, qd: pixel-quad 0..6
    float4 v4 = make_float4(0.f, 0.f, 0.f, 0.f);
    if (pixoff + qd*4 + 4 <= 100)          // guard: image row is 100 floats
      v4 = *(const float4*)(x + (size_t)(kt*32 + cc)*100 + pixoff + qd*4);
    dst[(qd*4+0)*40 + cc] = (f16)v4.x;
    dst[(qd*4+1)*40 + cc] = (f16)v4.y;
    dst[(qd*4+2)*40 + cc] = (f16)v4.z;
    dst[(qd*4+3)*40 + cc] = (f16)v4.w;
  }
}

__global__ __launch_bounds__(256) void k_feat(
    const float* __restrict__ spt, const float* __restrict__ qry,
    const f16* __restrict__ W65, const float* __restrict__ wsum,
    const float* __restrict__ gg, const float* __restrict__ bb,
    f16* __restrict__ s16, f16* __restrict__ q16,
    float* __restrict__ sptm, float* __restrict__ qrym)
{
  __shared__ f16 Xs[2][32*40];
  __shared__ float Ys[32*85];
  __shared__ float sg[64], sb[64], sw[64];
  const int b = blockIdx.x;
  const int n = b >> 2, quarter = b & 3;
  const int pixbase = quarter * 28;
  const float* x; f16* out16; float* mout;
  if (n < 5){ x = spt + (size_t)n*64000; out16 = s16 + (size_t)n*7168; mout = sptm + n*100; }
  else { x = qry + (size_t)(n-5)*64000; out16 = q16 + (size_t)(n-5)*7168; mout = qrym + (size_t)(n-5)*100; }
  const int t = threadIdx.x, l = t & 63, wid = t >> 6;
  const int r16 = l & 15, kbq = (l >> 4) & 3;

  // zero Xs rows 28..31 in both buffers (N-tile pad)
  if (t < 40){
    const f16x8 z8 = {(f16)0,(f16)0,(f16)0,(f16)0,(f16)0,(f16)0,(f16)0,(f16)0};
    const int bu = t / 20, rr = (t % 20) / 5, o = t % 5;
    *(f16x8*)(Xs[bu] + (28 + rr)*40 + o*8) = z8;
  }
  if (t >= 64 && t < 128){ sg[t-64] = gg[t-64]; sb[t-64] = bb[t-64]; sw[t-64] = wsum[t-64]; }

  int mts[3], nts[3];
  #pragma unroll
  for (int s = 0; s < 3; s++){ const int mn = wid + s*4; mts[s] = mn >> 1; nts[s] = mn & 1; }
  f32x4 acc[3];
  #pragma unroll
  for (int s = 0; s < 3; s++) acc[s] = (f32x4){0.f,0.f,0.f,0.f};

  feat_stage4(x, pixbase, 0, Xs[0], t);
  __syncthreads();
  for (int kt = 0; kt < 20; kt++){
    if (kt < 19) feat_stage4(x, pixbase, kt+1, Xs[(kt+1)&1], t);
    const f16* xb = Xs[kt&1];
    #pragma unroll
    for (int s = 0; s < 3; s++){
      const int mn = wid + s*4;
      if (mn < 10){
        const f16x8 a8 = *(const f16x8*)(W65 + (size_t)(mts[s]*16 + r16)*640 + kt*32 + kbq*8);
        const f16x8 b8 = *(const f16x8*)(xb + (nts[s]*16 + r16)*40 + kbq*8);
        acc[s] = __builtin_amdgcn_mfma_f32_16x16x32_f16(a8, b8, acc[s], 0, 0, 0);
      }
    }
    __syncthreads();
  }
  #pragma unroll
  for (int s = 0; s < 3; s++){
    const int mn = wid + s*4;
    if (mn < 10){
      const int col = nts[s]*16 + r16, rb = mts[s]*16 + kbq*4;
      #pragma unroll
      for (int r = 0; r < 4; r++) Ys[col*85 + rb + r] = acc[s][r];
    }
  }
  __syncthreads();

  if (t < 224){
    const int pixl = t >> 3, oo = t & 7;        // pixl 0..27, oo 0..7 (8 channels each)
    const int pixg = pixbase + pixl;
    const bool ok = (pixg < 100);
    const float m = Ys[pixl*85 + 64] * (1.f/640.f);
    float yr[8]; float ssq = 0.f;
    #pragma unroll
    for (int j = 0; j < 8; j++){
      const int o = oo*8 + j;
      float yv = 0.f;
      if (ok) yv = fmaxf(sg[o]*(Ys[pixl*85 + o] - sw[o]*m) + sb[o], 0.f);
      yr[j] = yv; ssq += yv*yv;
    }
    ssq += __shfl_xor(ssq, 1); ssq += __shfl_xor(ssq, 2); ssq += __shfl_xor(ssq, 4);
    const float inv = ok ? (1.f / fmaxf(sqrtf(ssq), 1e-8f)) : 0.f;
    #pragma unroll
    for (int j2 = 0; j2 < 4; j2++){
      f16x2 hv = { (f16)(yr[2*j2]*inv), (f16)(yr[2*j2+1]*inv) };
      *(f16x2*)(out16 + (size_t)pixg*64 + oo*8 + 2*j2) = hv;
    }
    if (oo == 0 && ok) mout[pixg] = m;
  }
}

// ---------------- k_z: corr + layer0 as three MFMA GEMMs -> z (f16) ----------------
__global__ __launch_bounds__(256) void k_z(
    const f16* __restrict__ s16, const f16* __restrict__ q16,
    const float* __restrict__ cp, const f16* __restrict__ MuF, const f16* __restrict__ MhF,
    f16* __restrict__ z)
{
  __shared__ __align__(16) f16 smz[112*120 + 112*120 + 16];
  f16* cbT = smz;
  f16* tS  = smz + 112*120;
  const int pair = blockIdx.x;
  const int q = pair / WAYT, w = pair % WAYT;
  const int t = threadIdx.x, l = t & 63, wid = t >> 6;
  const int r16 = l & 15, kb = (l >> 4) & 3;

  {
    const f16x8 z8 = {(f16)0,(f16)0,(f16)0,(f16)0,(f16)0,(f16)0,(f16)0,(f16)0};
    if (t < 112){
      *(f16x8*)(cbT + t*120 + 112) = z8;
      *(f16x8*)(tS  + t*120 + 112) = z8;
    }
    if (t < 16) tS[112*120 + t] = (f16)0;
    if (t >= 240 && t < 248) tS[t - 240] = (f16)0;
  }

  const f16* sbase = s16 + (size_t)w * 7168;
  const f16* qbase = q16 + (size_t)q * 7168;

  for (int mn = wid; mn < 49; mn += 4){
    const int mt = mn / 7, nt = mn - (mn/7)*7;
    const f16x8 a0 = *(const f16x8*)(sbase + (mt*16 + r16)*64 + kb*8);
    const f16x8 a1 = *(const f16x8*)(sbase + (mt*16 + r16)*64 + 32 + kb*8);
    const f16x8 b0 = *(const f16x8*)(qbase + (nt*16 + r16)*64 + kb*8);
    const f16x8 b1 = *(const f16x8*)(qbase + (nt*16 + r16)*64 + 32 + kb*8);
    f32x4 acc = {0.f,0.f,0.f,0.f};
    acc = __builtin_amdgcn_mfma_f32_16x16x32_f16(a0, b0, acc, 0, 0, 0);
    acc = __builtin_amdgcn_mfma_f32_16x16x32_f16(a1, b1, acc, 0, 0, 0);
    union { f16x4 v4; f16x2 h2[2]; } hv;
    hv.h2[0] = pkrtz(acc[0], acc[1]);
    hv.h2[1] = pkrtz(acc[2], acc[3]);
    *(f16x4*)(cbT + (nt*16 + r16)*120 + mt*16 + kb*4) = hv.v4;
  }
  __syncthreads();

  const float g20 = cp[CP_SC+0], b20 = cp[CP_SC+1];
  for (int mn = wid; mn < 49; mn += 4){
    const int mt = mn / 7, nt = mn - (mn/7)*7;
    f32x4 acc = {0.f,0.f,0.f,0.f};
    #pragma unroll
    for (int kt = 0; kt < 4; kt++){
      const f16x8 a8 = *(const f16x8*)(cbT + (mt*16 + r16)*120 + kt*32 + kb*8);
      const f16x8 b8 = *(const f16x8*)(MuF + (size_t)(nt*4 + kt)*512 + l*8);
      acc = __builtin_amdgcn_mfma_f32_16x16x32_f16(a8, b8, acc, 0, 0, 0);
    }
    union { f16x4 v4; f16x2 h2[2]; } hv;
    hv.h2[0] = pkrtz(fmaxf(g20*acc[0] + b20, 0.f), fmaxf(g20*acc[1] + b20, 0.f));
    hv.h2[1] = pkrtz(fmaxf(g20*acc[2] + b20, 0.f), fmaxf(g20*acc[3] + b20, 0.f));
    *(f16x4*)(tS + (nt*16 + r16)*120 + mt*16 + kb*4) = hv.v4;
  }
  __syncthreads();

  const float g10 = cp[CP_SC+2], b10 = cp[CP_SC+3];
  for (int mn = wid; mn < 49; mn += 4){
    const int mt = mn / 7, nt = mn - (mn/7)*7;
    f32x4 acc = {0.f,0.f,0.f,0.f};
    #pragma unroll
    for (int kt = 0; kt < 4; kt++){
      const f16x8 a8 = *(const f16x8*)(tS + (mt*16 + r16)*120 + kt*32 + kb*8);
      const f16x8 b8 = *(const f16x8*)(MhF + (size_t)(nt*4 + kt)*512 + l*8);
      acc = __builtin_amdgcn_mfma_f32_16x16x32_f16(a8, b8, acc, 0, 0, 0);
    }
    const int hw = nt*16 + r16;
    if (hw < 100){
      #pragma unroll
      for (int r = 0; r < 4; r++){
        const int uv = mt*16 + kb*4 + r;
        if (uv < 100) z[(size_t)pair*10000 + uv*100 + hw] = (f16)(g10*acc[r] + b10);
      }
    }
  }
}

// ---------------- k_l1 (unchanged from round 7) ----------------
__global__ __launch_bounds__(256, 6) void k_l1(
    const f16* __restrict__ z, const float* __restrict__ cp,
    const f16* __restrict__ Apack, const f16* __restrict__ Wf2, f16* __restrict__ F)
{
  __shared__ f16 z3[3*1216];
  __shared__ f16 Gs[9*GS_STRIDE];
  const int u = blockIdx.x, pair = blockIdx.y;
  const int t = threadIdx.x, l = t & 63, wid = t >> 6;
  const int r16 = l & 15, kb = (l >> 4) & 3;
  const int khi = kb & 1, half = kb >> 1;

  for (int e = t; e < 1824; e += 256){
    const int du = e / 608, c2 = e - du*608;
    const int ur = u + du - 1;
    const int colb = c2*2;
    const int g = colb - 100;
    f16x2 v = {(f16)0, (f16)0};
    if (ur >= 0 && ur <= 9 && g >= 0 && g < 1000)
      v = *(const f16x2*)(z + (size_t)pair*10000 + ur*1000 + g);
    *(f16x2*)(z3 + du*1216 + colb) = v;
  }

  f16x2 Ac2[4], Bc2[4];
  {
    const float4 a4a = ((const float4*)(cp + CP_A))[khi*2];
    const float4 a4b = ((const float4*)(cp + CP_A))[khi*2+1];
    const float4 b4a = ((const float4*)(cp + CP_B))[khi*2];
    const float4 b4b = ((const float4*)(cp + CP_B))[khi*2+1];
    Ac2[0] = (f16x2){(f16)a4a.x,(f16)a4a.y}; Ac2[1] = (f16x2){(f16)a4a.z,(f16)a4a.w};
    Ac2[2] = (f16x2){(f16)a4b.x,(f16)a4b.y}; Ac2[3] = (f16x2){(f16)a4b.z,(f16)a4b.w};
    Bc2[0] = (f16x2){(f16)b4a.x,(f16)b4a.y}; Bc2[1] = (f16x2){(f16)b4a.z,(f16)b4a.w};
    Bc2[2] = (f16x2){(f16)b4b.x,(f16)b4b.y}; Bc2[3] = (f16x2){(f16)b4b.z,(f16)b4b.w};
  }
  f16x8 af[5];
  #pragma unroll
  for (int p = 0; p < 5; p++) af[p] = ((const f16x8*)Apack)[p*64 + l];
  const f16x4 wf = ((const f16x4*)Wf2)[l];

  float gv[4], bm[4], bv0[4], bv9[4];
  #pragma unroll
  for (int r = 0; r < 4; r++){
    const int co = kb*4 + r;
    gv[r] = cp[CP_G2 + co];
    const float b0 = cp[CP_B2 + co];
    float c0 = 0.f, cv0 = 0.f, cv9 = 0.f;
    #pragma unroll
    for (int du = 0; du < 3; du++){
      const int ur = u + du - 1;
      const float t0 = cp[CP_T9 + (du*3+0)*16 + co];
      const float t1 = cp[CP_T9 + (du*3+1)*16 + co];
      const float t2 = cp[CP_T9 + (du*3+2)*16 + co];
      if (ur < 0 || ur > 9) c0 += t0 + t1 + t2;
      else { cv0 += t0; cv9 += t2; }
    }
    bm[r]  = b0 - gv[r]*c0;
    bv0[r] = bm[r] - gv[r]*cv0;
    bv9[r] = bm[r] - gv[r]*cv9;
  }
  int zoffE[5];
  #pragma unroll
  for (int p = 0; p < 5; p++){
    const int tap = 2*p + half;
    const int du = (tap <= 8) ? tap/3 : 0;
    const int dv = (tap <= 8) ? tap%3 : 0;
    zoffE[p] = du*1216 + dv*100;
  }
  __syncthreads();

  const f16x2 zero2 = {(f16)0, (f16)0};
  #pragma unroll 1
  for (int i = 0; i < 16; i++){
    const int cbase = wid*256 + i*16;
    if (cbase >= 1008) break;
    const int c = cbase + r16;
    const int v = (c * 5243) >> 19;
    f32x4 acc = {0.f,0.f,0.f,0.f};
    #pragma unroll
    for (int p = 0; p < 5; p++){
      const f16 zv = z3[zoffE[p] + c];
      const f16x2 zz = {zv, zv};
      union { f16x8 v8; f16x2 h2[4]; } bu;
      #pragma unroll
      for (int j2 = 0; j2 < 4; j2++){
        f16x2 r2 = Ac2[j2] * zz + Bc2[j2];
        bu.h2[j2] = __builtin_elementwise_max(r2, zero2);
      }
      acc = __builtin_amdgcn_mfma_f32_16x16x32_f16(af[p], bu.v8, acc, 0, 0, 0);
    }
    const bool isv0 = (v == 0), isv9 = (v == 9);
    float rr[4];
    #pragma unroll
    for (int r = 0; r < 4; r++){
      const float bsel = isv0 ? bv0[r] : (isv9 ? bv9[r] : bm[r]);
      rr[r] = fmaxf(fmaf(gv[r], acc[r], bsel), 0.f);
    }
    union { f16x4 v4; f16x2 h2[2]; } t1u;
    t1u.h2[0] = pkrtz(rr[0], rr[1]);
    t1u.h2[1] = pkrtz(rr[2], rr[3]);
    f32x4 g = {0.f,0.f,0.f,0.f};
    g = __builtin_amdgcn_mfma_f32_16x16x16f16(wf, t1u.v4, g, 0, 0, 0);
    #pragma unroll
    for (int r = 0; r < 4; r++){
      const int tap = kb*4 + r;
      if (tap <= 8) Gs[tap*GS_STRIDE + 16 + c] = (f16)g[r];
    }
  }
  __syncthreads();

  const float Kc = cp[CP_SC+4];
  #pragma unroll 1
  for (int oo = 0; oo < 4; oo++){
    const int c = t + oo*256;
    if (c < 1000){
      const int hw = c - ((c * 5243) >> 19) * 100;
      const int h = (hw * 205) >> 11, w2 = hw - h*10;
      float o = Kc;
      #pragma unroll
      for (int dh = 0; dh < 3; dh++){
        #pragma unroll
        for (int dw = 0; dw < 3; dw++){
          const bool okg = ((unsigned)(h + dh - 1) <= 9u) && ((unsigned)(w2 + dw - 1) <= 9u);
          const float gvv = (float)Gs[(dh*3+dw)*GS_STRIDE + 16 + c + (dh-1)*10 + (dw-1)];
          o += okg ? gvv : 0.f;
        }
      }
      F[(size_t)pair*10000 + u*1000 + c] = (f16)o;
    }
  }
}

// ---------------- attn_a: gnorm + softmax -> asq[pair][256] (zero-padded rows) ----------------
__global__ __launch_bounds__(256) void k_attn_a(const f16* __restrict__ F, float* __restrict__ asq)
{
  __shared__ float fb[100*101 + 4];
  __shared__ float isc[100], ccs[100], isr[100], ccr[100];
  const int pair = blockIdx.x;
  const int t = threadIdx.x;
  const float L2T = 1.4426950408889634f * 0.2f;

  for (int e = t; e < 10000; e += 256)
    fb[(e/100)*101 + (e%100)] = (float)F[(size_t)pair*10000 + e];
  __syncthreads();

  {
    const int line = t & 127;
    const bool isCol = t < 128;
    if (line < 100){
      const int base = isCol ? line : line*101;
      const int stride = isCol ? 101 : 1;
      float s = 0.f, ss = 0.f;
      for (int i = 0; i < 100; i++){ const float x = fb[base + i*stride]; s += x; ss += x*x; }
      const float m = s * 0.01f;
      const float var = (ss - 100.f*m*m) * (1.f/99.f);
      const float is2 = rsqrtf(var + 1e-5f) * L2T;
      float S = 0.f;
      for (int i = 0; i < 100; i++) S += exp2f((fb[base + i*stride] - m) * is2);
      const float cc = m*is2 + log2f(S);
      if (isCol){ isc[line] = is2; ccs[line] = cc; }
      else      { isr[line] = is2; ccr[line] = cc; }
    }
  }
  __syncthreads();
  {
    const int line = t & 127;
    if (line < 100){
      if (t < 128){
        float a = 0.f;
        for (int k = 0; k < 100; k++)
          a += exp2f(fb[line*101 + k] * isc[k] - ccs[k]);
        asq[(size_t)pair*256 + line] = a;       // a_s
      } else {
        float a = 0.f;
        for (int k = 0; k < 100; k++)
          a += exp2f(fb[k*101 + line] * isr[k] - ccr[k]);
        asq[(size_t)pair*256 + 128 + line] = a; // a_q
      }
    } else {
      asq[(size_t)pair*256 + t] = 0.f;          // zero pads for GEMM K reads
    }
  }
}

// ---------------- spqp: 350 blocks. b<50: sp GEMM; b>=50: qp GEMM split by c-half ----------------
__global__ __launch_bounds__(256) void k_spqp(
    const float* __restrict__ spt, const float* __restrict__ qry,
    const float* __restrict__ asq, float* __restrict__ P)
{
  const int b = blockIdx.x;
  const int t = threadIdx.x, l = t & 63, wid = t >> 6;
  const int r16 = l & 15, kb = (l >> 4) & 3;

  if (b < 50){
    const int w = b / 10, c0 = (b % 10) * 64;
    const int c = c0 + wid*16 + r16;
    f16x8 bf[4];
    #pragma unroll
    for (int kt = 0; kt < 4; kt++){
      const int kbase = kt*32 + kb*8;
      float v[8];
      #pragma unroll
      for (int j = 0; j < 8; j++){
        const int k = kbase + j;
        v[j] = (k < 100) ? spt[(size_t)w*64000 + (size_t)c*100 + k] : 0.f;
      }
      union { f16x8 v8; f16x2 h2[4]; } u;
      #pragma unroll
      for (int j2 = 0; j2 < 4; j2++) u.h2[j2] = pkrtz(v[2*j2], v[2*j2+1]);
      bf[kt] = u.v8;
    }
    #pragma unroll 1
    for (int mt = 0; mt < 10; mt++){
      const int qr = mt*16 + r16;
      f32x4 acc = {0.f,0.f,0.f,0.f};
      #pragma unroll
      for (int kt = 0; kt < 4; kt++){
        const int kbase = kt*32 + kb*8;
        float v[8];
        #pragma unroll
        for (int j = 0; j < 8; j++)
          v[j] = (qr < 150) ? asq[(size_t)(qr*5 + w)*256 + kbase + j] : 0.f;
        union { f16x8 v8; f16x2 h2[4]; } u;
        #pragma unroll
        for (int j2 = 0; j2 < 4; j2++) u.h2[j2] = pkrtz(v[2*j2], v[2*j2+1]);
        acc = __builtin_amdgcn_mfma_f32_16x16x32_f16(u.v8, bf[kt], acc, 0, 0, 0);
      }
      #pragma unroll
      for (int r = 0; r < 4; r++){
        const int q2 = mt*16 + kb*4 + r;
        if (q2 < 150) P[(size_t)(q2*5 + w)*1280 + c0 + wid*16 + (l & 15)] = acc[r];
      }
    }
  } else {
    const int idx = b - 50, q = idx >> 1, chalf = idx & 1;
    f16x8 af[4];
    #pragma unroll
    for (int kt = 0; kt < 4; kt++){
      const int kbase = kt*32 + kb*8;
      float v[8];
      #pragma unroll
      for (int j = 0; j < 8; j++)
        v[j] = (r16 < 5) ? asq[(size_t)(q*5 + r16)*256 + 128 + kbase + j] : 0.f;
      union { f16x8 v8; f16x2 h2[4]; } u;
      #pragma unroll
      for (int j2 = 0; j2 < 4; j2++) u.h2[j2] = pkrtz(v[2*j2], v[2*j2+1]);
      af[kt] = u.v8;
    }
    #pragma unroll 1
    for (int nt = chalf*20 + wid; nt < chalf*20 + 20; nt += 4){
      const int c = nt*16 + r16;
      f32x4 acc = {0.f,0.f,0.f,0.f};
      #pragma unroll
      for (int kt = 0; kt < 4; kt++){
        const int kbase = kt*32 + kb*8;
        float v[8];
        #pragma unroll
        for (int j = 0; j < 8; j++){
          const int k = kbase + j;
          v[j] = (k < 100) ? qry[(size_t)q*64000 + (size_t)c*100 + k] : 0.f;
        }
        union { f16x8 v8; f16x2 h2[4]; } u;
        #pragma unroll
        for (int j2 = 0; j2 < 4; j2++) u.h2[j2] = pkrtz(v[2*j2], v[2*j2+1]);
        acc = __builtin_amdgcn_mfma_f32_16x16x32_f16(af[kt], u.v8, acc, 0, 0, 0);
      }
      #pragma unroll
      for (int r = 0; r < 4; r++){
        const int w2 = kb*4 + r;
        if (w2 < 5) P[(size_t)(q*5 + w2)*1280 + 640 + nt*16 + (l & 15)] = acc[r];
      }
    }
  }
}

// ---------------- cos: mean-correct + cosine per pair ----------------
__global__ __launch_bounds__(256) void k_cos(
    const float* __restrict__ P, const float* __restrict__ asq,
    const float* __restrict__ sptm, const float* __restrict__ qrym,
    float* __restrict__ out)
{
  __shared__ float pred[4];
  __shared__ float MsMq[2];
  __shared__ float red[12];
  const int pair = blockIdx.x;
  const int q = pair / WAYT, w = pair % WAYT;
  const int t = threadIdx.x, wid = t >> 6;

  float pm = 0.f;
  if (t < 100) pm = asq[(size_t)pair*256 + t] * sptm[w*100 + t];
  else if (t >= 128 && t < 228) pm = asq[(size_t)pair*256 + t] * qrym[q*100 + (t - 128)];
  #pragma unroll
  for (int m = 1; m < 64; m <<= 1) pm += __shfl_xor(pm, m);
  if ((t & 63) == 0) pred[wid] = pm;
  __syncthreads();
  if (t == 0) MsMq[0] = pred[0] + pred[1];
  if (t == 1) MsMq[1] = pred[2] + pred[3];
  __syncthreads();
  const float Ms = MsMq[0], Mq = MsMq[1];

  float d0 = 0.f, d1 = 0.f, d2 = 0.f;
  for (int c = t; c < 640; c += 256){
    const float sp = P[(size_t)pair*1280 + c] - Ms;
    const float qp = P[(size_t)pair*1280 + 640 + c] - Mq;
    d0 += sp*qp; d1 += sp*sp; d2 += qp*qp;
  }
  #pragma unroll
  for (int m = 1; m < 64; m <<= 1){
    d0 += __shfl_xor(d0, m); d1 += __shfl_xor(d1, m); d2 += __shfl_xor(d2, m);
  }
  if ((t & 63) == 0){ red[wid*3+0] = d0; red[wid*3+1] = d1; red[wid*3+2] = d2; }
  __syncthreads();
  if (t == 0){
    float e0 = 0.f, e1 = 0.f, e2 = 0.f;
    #pragma unroll
    for (int k = 0; k < 4; k++){ e0 += red[k*3]; e1 += red[k*3+1]; e2 += red[k*3+2]; }
    const float den = fmaxf(sqrtf(e1), 1e-8f) * fmaxf(sqrtf(e2), 1e-8f);
    out[pair] = (e0 / den) * 5.0f;
  }
}

extern "C" void kernel_launch(void* const* d_in, const int* in_sizes, int n_in,
                              void* d_out, int out_size, void* d_ws, size_t ws_size,
                              hipStream_t stream)
{
  (void)in_sizes; (void)n_in; (void)out_size; (void)ws_size;
  const float* spt = (const float*)d_in[0];
  const float* qry = (const float*)d_in[1];
  const float* Wc  = (const float*)d_in[2];
  const float* gc  = (const float*)d_in[3];
  const float* bc  = (const float*)d_in[4];

  float* ws    = (float*)d_ws;
  float* cp    = ws;                          // 256
  float* wsum  = ws + 256;                    // 64
  float* sptm  = ws + 320;                    // 500
  float* qrym  = ws + 820;                    // 15000 -> 15820, pad 15872
  f16*  Apack  = (f16*)(ws + 15872);          // 2560 f16
  f16*  Wf2    = (f16*)(ws + 17152);          // 256 f16
  f16*  W65    = (f16*)(ws + 17280);          // 51200 f16
  f16*  MuF    = (f16*)(ws + 42880);          // 14336 f16
  f16*  MhF    = (f16*)(ws + 50048);          // 14336 f16
  f16*  s16    = (f16*)(ws + 57216);          // 35840 f16
  f16*  q16    = (f16*)(ws + 75136);          // 1075200 f16
  f16*  z      = (f16*)(ws + 612736);         // 7.5M f16
  f16*  F      = (f16*)(ws + 4362736);        // 7.5M f16 (end 32.45 MB)
  // aliases (lifetime-disjoint):
  float* asq   = ws + 75136;                  // over q16 (dead after k_z); 192000 f32
  float* P     = ws + 612736;                 // over z   (dead after k_l1); 960000 f32

  k_prep_all<<<41, 256, 0, stream>>>(
      Wc,
      (const float*)d_in[5],  (const float*)d_in[6],  (const float*)d_in[7],
      (const float*)d_in[8],  (const float*)d_in[9],  (const float*)d_in[10],
      (const float*)d_in[11], (const float*)d_in[12], (const float*)d_in[13],
      (const float*)d_in[14], (const float*)d_in[15], (const float*)d_in[16],
      (const float*)d_in[17], (const float*)d_in[18], (const float*)d_in[19],
      (const float*)d_in[20], (const float*)d_in[21], (const float*)d_in[22],
      cp, Apack, Wf2, MuF, MhF, W65, wsum);
  k_feat<<<620, 256, 0, stream>>>(spt, qry, W65, wsum, gc, bc, s16, q16, sptm, qrym);
  k_z<<<NQT*WAYT, 256, 0, stream>>>(s16, q16, cp, MuF, MhF, z);
  {
    dim3 grid(10, NQT*WAYT);
    k_l1<<<grid, 256, 0, stream>>>(z, cp, Apack, Wf2, F);
  }
  k_attn_a<<<NQT*WAYT, 256, 0, stream>>>(F, asq);
  k_spqp<<<350, 256, 0, stream>>>(spt, qry, asq, P);
  k_cos<<<NQT*WAYT, 256, 0, stream>>>(P, asq, sptm, qrym, (float*)d_out);
}